// Round 18
// baseline (128.637 us; speedup 1.0000x reference)
//
#include <hip/hip_runtime.h>
#include <hip/hip_bf16.h>
#include <math.h>

#define NCLS 10
#define NTOT 8192
#define NTIL 64                    // 128-row panels per side
#define NJT 8                      // pass-2 j-tiles per block
#define NJG (NTOT / (128 * NJT))   // 8
#define NPMAX 9472                 // padded permuted rows upper bound
#define MAXSLOT 32                 // pass-1 top4 slots per row
#define G1 3072                    // pass-1 grid upper bound (early-exit)

using short8 = __attribute__((ext_vector_type(8))) short;
using f32x4  = __attribute__((ext_vector_type(4))) float;

__device__ __forceinline__ float digammaf_dev(float x) {
    float r = 0.0f;
    while (x < 6.0f) { r -= 1.0f / x; x += 1.0f; }
    float inv = 1.0f / x;
    float inv2 = inv * inv;
    float s = logf(x) - 0.5f * inv
            - inv2 * (0.083333333333f - inv2 * (0.0083333333333f - inv2 * 0.0039682539683f));
    return r + s;
}

__device__ __forceinline__ void cmpswap(float& a, float& b) {
    float lo = fminf(a, b), hi = fmaxf(a, b);
    a = lo; b = hi;
}

__device__ __forceinline__ void ins7(float v, float& b0, float& b1, float& b2, float& b3) {
    float x0 = fminf(b0, v); float c0 = fmaxf(b0, v);
    float x1 = fminf(b1, c0); float c1 = fmaxf(b1, c0);
    float x2 = fminf(b2, c1); float c2 = fmaxf(b2, c1);
    float x3 = fminf(b3, c2);
    b0 = x0; b1 = x1; b2 = x2; b3 = x3;
}

__device__ __forceinline__ void bmerge(int mk, float& v0, float& v1, float& v2, float& v3) {
    float u0 = __shfl_xor(v0, mk), u1 = __shfl_xor(v1, mk);
    float u2 = __shfl_xor(v2, mk), u3 = __shfl_xor(v3, mk);
    float m0 = fminf(v0, u3), m1 = fminf(v1, u2);
    float m2 = fminf(v2, u1), m3 = fminf(v3, u0);
    cmpswap(m0, m2); cmpswap(m1, m3);
    cmpswap(m0, m1); cmpswap(m2, m3);
    v0 = m0; v1 = m1; v2 = m2; v3 = m3;
}

__device__ __forceinline__ void gload_lds16(const void* g, void* s) {
    __builtin_amdgcn_global_load_lds((const __attribute__((address_space(1))) void*)g,
                                     (__attribute__((address_space(3))) void*)s, 16, 0, 0);
}

// Shared chain (both passes, per output element, fixed K-order):
//   s0: A_hi0*B_hi0 (kk0,kk1) then A_lo0*B_hi0 (kk0,kk1)
//   s1: A_hi1*B_hi1 then A_lo1*B_hi1
//   s2: A_hi0*B_lo0
//   s3: A_hi1*B_lo1
// B panel short-offsets per step:
__constant__ const int Bpan_[4] = {0, 64, 128, 192};

// per row: sq (fp32), XS[row][0..127]=hi(bf16), [128..255]=lo(bf16)
__global__ void prep_kernel(const float* __restrict__ X,
                            float* __restrict__ sq, unsigned short* __restrict__ XS) {
    int wave = threadIdx.x >> 6, lane = threadIdx.x & 63;
    int row = blockIdx.x * 4 + wave;
    float2 v = *(const float2*)(X + (size_t)row * 128 + lane * 2);
    __hip_bfloat16 h0 = __float2bfloat16(v.x);
    __hip_bfloat16 h1 = __float2bfloat16(v.y);
    float hf0 = __bfloat162float(h0), hf1 = __bfloat162float(h1);
    __hip_bfloat16 l0 = __float2bfloat16(v.x - hf0);
    __hip_bfloat16 l1 = __float2bfloat16(v.y - hf1);
    ushort2 hp, lp;
    hp.x = *(unsigned short*)&h0; hp.y = *(unsigned short*)&h1;
    lp.x = *(unsigned short*)&l0; lp.y = *(unsigned short*)&l1;
    *(ushort2*)(XS + (size_t)row * 256 + lane * 2) = hp;
    *(ushort2*)(XS + (size_t)row * 256 + 128 + lane * 2) = lp;
    float s = fmaf(v.x, v.x, v.y * v.y);
    #pragma unroll
    for (int off = 32; off > 0; off >>= 1) s += __shfl_down(s, off);
    if (lane == 0) sq[row] = s;
}

// plan (1 block, 256 thr): fused histogram + prefix + sOff + yP init.
// plan[c]=rowBase, [10+c]=T, [20+c]=nsl(=T), [30+c]=cumBlk (2*T*T), [40]=nBlocks.
__global__ void plan_kernel(const int* __restrict__ y, int* __restrict__ plan,
                            int* __restrict__ sOff, int* __restrict__ cls,
                            int* __restrict__ yP) {
    __shared__ int hist[32][NCLS];
    __shared__ int sT[NCLS], sBase[NCLS];
    const int t = threadIdx.x;
    for (int i = t; i < 32 * NCLS; i += 256) (&hist[0][0])[i] = 0;
    for (int i = t; i < NPMAX; i += 256) yP[i] = -1;
    __syncthreads();
    {
        const int base = t * 32;
        const int chunk = t >> 3;
        #pragma unroll 8
        for (int k = 0; k < 32; ++k)
            atomicAdd(&hist[chunk][y[base + k]], 1);
    }
    __syncthreads();
    if (t < NCLS) {
        int run = 0;
        #pragma unroll 8
        for (int b = 0; b < 32; ++b) {
            sOff[b * NCLS + t] = run;
            run += hist[b][t];
        }
        cls[t] = run;
        sT[t] = (run + 127) >> 7;
    }
    __syncthreads();
    if (t == 0) {
        int rowBase = 0, cum = 0;
        for (int q = 0; q < NCLS; ++q) {
            int T = sT[q];
            sBase[q] = rowBase;
            plan[q] = rowBase;
            plan[10 + q] = T;
            plan[20 + q] = T;
            plan[30 + q] = cum;
            rowBase += T << 7;
            cum += 2 * T * T;
        }
        plan[40] = cum;
    }
    __syncthreads();
    if (t < NCLS) {
        int rb = sBase[t];
        #pragma unroll 8
        for (int b = 0; b < 32; ++b) sOff[b * NCLS + t] += rb;
    }
}

// deterministic class-bucketed scatter: XS -> XSP (+ sqP, yP, idxP)
__global__ void scatter_kernel(const int* __restrict__ y, const float* __restrict__ sq,
                               const unsigned short* __restrict__ XS,
                               const int* __restrict__ sOff,
                               unsigned short* __restrict__ XSP, float* __restrict__ sqP,
                               int* __restrict__ yP, int* __restrict__ idxP) {
    __shared__ int yloc[256];
    __shared__ int dstloc[256];
    const int b = blockIdx.x, t = threadIdx.x;
    const int gid = b * 256 + t;
    const int yv = y[gid];
    yloc[t] = yv;
    __syncthreads();
    int rank = 0;
    for (int k = 0; k < 256; ++k) rank += (k < t && yloc[k] == yv) ? 1 : 0;
    const int dst = sOff[b * NCLS + yv] + rank;
    dstloc[t] = dst;
    sqP[dst] = sq[gid];
    yP[dst] = yv;
    idxP[dst] = gid;
    __syncthreads();
    const int w = t >> 6, l = t & 63;
    for (int r = w; r < 256; r += 4) {
        int d = dstloc[r];
        *(ushort4*)(XSP + (size_t)d * 256 + l * 4) =
            *(const ushort4*)(XS + (size_t)(b * 256 + r) * 256 + l * 4);
    }
}

// Pass 1 (class-bucketed, 64x128 tiles, hybrid-A + shared chain).
// A_hi frags in regs; A_lo resident LDS (2x8KB); B dbuf 2x16KB. 4 steps/tile.
__global__ __launch_bounds__(256, 1)
void pass1_kernel(const unsigned short* __restrict__ XSP, const int* __restrict__ yP,
                  const float* __restrict__ sqP, const int* __restrict__ plan,
                  float* __restrict__ top4pP) {
    const int bid = blockIdx.x;
    if (bid >= plan[40]) return;
    __shared__ __align__(16) char smem[49152];   // Alo0 @0, Alo1 @8192, B dbuf @16384

    const int t = threadIdx.x;
    const int w = t >> 6, l = t & 63;
    const int wr = w >> 1, wc = w & 1;
    const int lg = l >> 4, lo16 = l & 15;

    int cc = 0;
    #pragma unroll
    for (int q = 1; q < NCLS; ++q) if (bid >= plan[30 + q]) cc = q;
    const int rowBase = plan[cc], T = plan[10 + cc];
    const int local = bid - plan[30 + cc];
    const int jt = local % T;
    const int itile2 = local / T;
    const int ibase = rowBase + (itile2 >> 1) * 128 + (itile2 & 1) * 64;
    const int jbase = rowBase + jt * 128;

    float sqi[8]; int yi[8];
    #pragma unroll
    for (int mi = 0; mi < 2; ++mi)
        #pragma unroll
        for (int r = 0; r < 4; ++r) {
            int row = ibase + wr * 32 + mi * 16 + lg * 4 + r;
            sqi[mi * 4 + r] = sqP[row];
            yi[mi * 4 + r] = yP[row];
        }
    float sqj[4]; int yj[4];
    #pragma unroll
    for (int ni = 0; ni < 4; ++ni) {
        int col = jbase + wc * 64 + ni * 16 + lo16;
        sqj[ni] = sqP[col];
        yj[ni] = yP[col];
    }

    const int swz = (lo16 & 7) << 4;
    unsigned aloff[2], boff[2];
    #pragma unroll
    for (int kk = 0; kk < 2; ++kk) {
        const int cA = (kk * 64 + lg * 16) ^ swz;
        aloff[kk] = (unsigned)((wr * 32 + lo16) * 128 + cA);
        boff[kk] = (unsigned)(16384 + (wc * 64 + lo16) * 128 + cA);
    }
    const int scol = ((t & 7) ^ ((t >> 3) & 7)) << 3;
    const int srow = t >> 3;   // 0..31

    // A_hi fragments -> registers (bytes identical to the swizzled LDS path)
    short8 aH[2][2][2];
    #pragma unroll
    for (int p = 0; p < 2; ++p)
        #pragma unroll
        for (int kk = 0; kk < 2; ++kk)
            #pragma unroll
            for (int mi = 0; mi < 2; ++mi)
                aH[p][kk][mi] = *(const short8*)(
                    XSP + (size_t)(ibase + wr * 32 + mi * 16 + lo16) * 256 + p * 64 + kk * 32 + lg * 8);

    auto STAGE_ALO = [&](int kpan, int dstOff) {   // 8KB: 64 rows x 64 shorts
        const unsigned short* g = XSP + (size_t)(ibase + srow) * 256 + kpan + scol;
        char* d = smem + dstOff + t * 16;
        gload_lds16(g, d);
        gload_lds16(g + 32 * 256, d + 4096);
    };
    auto STAGE_B = [&](int kpan, int par) {        // 16KB: 128 rows x 64 shorts
        const unsigned short* g = XSP + (size_t)(jbase + srow) * 256 + kpan + scol;
        char* d = smem + 16384 + par * 16384 + t * 16;
        gload_lds16(g, d);
        gload_lds16(g + 32 * 256, d + 4096);
        gload_lds16(g + 64 * 256, d + 8192);
        gload_lds16(g + 96 * 256, d + 12288);
    };

    float tp0[8], tp1[8], tp2[8], tp3[8];
    #pragma unroll
    for (int c = 0; c < 8; ++c) {
        tp0[c] = 1e30f; tp1[c] = 1e30f; tp2[c] = 1e30f; tp3[c] = 1e30f;
    }

    f32x4 acc[2][4];
    f32x4 zz = {0.0f, 0.0f, 0.0f, 0.0f};
    #pragma unroll
    for (int mi = 0; mi < 2; ++mi)
        #pragma unroll
        for (int ni = 0; ni < 4; ++ni) acc[mi][ni] = zz;

    STAGE_ALO(128, 0);
    STAGE_ALO(192, 8192);
    STAGE_B(0, 0);
    __syncthreads();

    #pragma unroll
    for (int s = 0; s < 4; ++s) {
        const int par = s & 1;
        if (s < 3) STAGE_B(Bpan_[s + 1], par ^ 1);
        const int p = s & 1;   // A_hi panel: s0->0, s1->1, s2->0, s3->1
        #pragma unroll
        for (int kk = 0; kk < 2; ++kk) {
            short8 bF[4];
            #pragma unroll
            for (int ni = 0; ni < 4; ++ni)
                bF[ni] = *(const short8*)(smem + boff[kk] + par * 16384 + ni * 2048);
            #pragma unroll
            for (int mi = 0; mi < 2; ++mi)
                #pragma unroll
                for (int ni = 0; ni < 4; ++ni)
                    acc[mi][ni] = __builtin_amdgcn_mfma_f32_16x16x32_bf16(
                        aH[p][kk][mi], bF[ni], acc[mi][ni], 0, 0, 0);
        }
        if (s < 2) {   // A_lo chain (panel s) on same B
            #pragma unroll
            for (int kk = 0; kk < 2; ++kk) {
                short8 bF[4], aL[2];
                #pragma unroll
                for (int ni = 0; ni < 4; ++ni)
                    bF[ni] = *(const short8*)(smem + boff[kk] + par * 16384 + ni * 2048);
                #pragma unroll
                for (int mi = 0; mi < 2; ++mi)
                    aL[mi] = *(const short8*)(smem + s * 8192 + aloff[kk] + mi * 2048);
                #pragma unroll
                for (int mi = 0; mi < 2; ++mi)
                    #pragma unroll
                    for (int ni = 0; ni < 4; ++ni)
                        acc[mi][ni] = __builtin_amdgcn_mfma_f32_16x16x32_bf16(
                            aL[mi], bF[ni], acc[mi][ni], 0, 0, 0);
            }
        }
        if (s == 3) {
            #pragma unroll
            for (int mi = 0; mi < 2; ++mi)
                #pragma unroll
                for (int r = 0; r < 4; ++r) {
                    const int idx = mi * 4 + r;
                    #pragma unroll
                    for (int ni = 0; ni < 4; ++ni) {
                        float d2 = fmaf(-2.0f, acc[mi][ni][r], sqi[idx] + sqj[ni]);
                        d2 = fmaxf(d2, 0.0f);
                        float v = (yi[idx] == yj[ni]) ? d2 : 1e30f;
                        ins7(v, tp0[idx], tp1[idx], tp2[idx], tp3[idx]);
                    }
                }
        }
        __syncthreads();
    }

    // cross-lane + cross-wave merge -> slot jt
    float* scrR = (float*)smem;
    #pragma unroll
    for (int idx = 0; idx < 8; ++idx) {
        float v0 = tp0[idx], v1 = tp1[idx], v2 = tp2[idx], v3 = tp3[idx];
        bmerge(1, v0, v1, v2, v3); bmerge(2, v0, v1, v2, v3);
        bmerge(4, v0, v1, v2, v3); bmerge(8, v0, v1, v2, v3);
        if (lo16 == 0) {
            int rl = wr * 32 + (idx >> 2) * 16 + lg * 4 + (idx & 3);
            float4 st; st.x = v0; st.y = v1; st.z = v2; st.w = v3;
            *(float4*)(scrR + rl * 8 + wc * 4) = st;
        }
    }
    __syncthreads();
    if (t < 64) {
        float4 qa = *(float4*)(scrR + t * 8);
        float4 qb = *(float4*)(scrR + t * 8 + 4);
        float b0 = qa.x, b1 = qa.y, b2 = qa.z, b3 = qa.w;
        ins7(qb.x, b0, b1, b2, b3); ins7(qb.y, b0, b1, b2, b3);
        ins7(qb.z, b0, b1, b2, b3); ins7(qb.w, b0, b1, b2, b3);
        size_t base = ((size_t)(ibase + t) * MAXSLOT + jt) * 4;
        top4pP[base + 0] = b0; top4pP[base + 1] = b1;
        top4pP[base + 2] = b2; top4pP[base + 3] = b3;
    }
}

// merge pass-1 slots -> anchor (scattered back to original index)
__global__ void anchorP_kernel(const float* __restrict__ top4pP, const int* __restrict__ yP,
                               const int* __restrict__ idxP, const int* __restrict__ plan,
                               float* __restrict__ anchor) {
    int r = blockIdx.x * 256 + threadIdx.x;
    int yv = yP[r];
    if (yv < 0) return;
    int nsl = plan[20 + yv];
    float b0 = 1e30f, b1 = 1e30f, b2 = 1e30f, b3 = 1e30f;
    const float4* q4 = (const float4*)(top4pP + (size_t)r * MAXSLOT * 4);
    for (int s = 0; s < nsl; ++s) {
        float4 q = q4[s];
        ins7(q.x, b0, b1, b2, b3); ins7(q.y, b0, b1, b2, b3);
        ins7(q.z, b0, b1, b2, b3); ins7(q.w, b0, b1, b2, b3);
    }
    anchor[idxP[r]] = b3;
}

// Pass 2: FULL-SQUARE count, hybrid-A + shared chain.
// A_hi frags in regs (loaded once/block); A_lo resident LDS (2x16KB, staged
// once/block); B streams 4 panels/jt through 2x16KB dbuf -> 4 barriers/jt,
// staged bytes 0.54MB/block (was 1.28MB). (256,1): ~220 VGPR, no 128-cap spill.
__global__ __launch_bounds__(256, 1)
void pass2_kernel(const unsigned short* __restrict__ XS, const float* __restrict__ sq,
                  const float* __restrict__ anchor, int* __restrict__ cntp) {
    __shared__ __align__(16) char smem[65536];   // Alo0 @0, Alo1 @16384, B dbuf @32768

    const int t = threadIdx.x;
    const int w = t >> 6, l = t & 63;
    const int wr = w >> 1, wc = w & 1;
    const int lg = l >> 4, lo16 = l & 15;

    // XCD-aware bijective swizzle (512 % 8 == 0)
    const int bid = blockIdx.x;
    const int wg = (bid & 7) * ((NTIL * NJG) >> 3) + (bid >> 3);
    const int it = wg % NTIL, jg = wg / NTIL;
    const int ibase = it * 128;
    const int jg0 = jg * (128 * NJT);

    float sqi[16]; float anc[16];
    #pragma unroll
    for (int mi = 0; mi < 4; ++mi)
        #pragma unroll
        for (int r = 0; r < 4; ++r) {
            int row = ibase + wr * 64 + mi * 16 + lg * 4 + r;
            sqi[mi * 4 + r] = sq[row];
            anc[mi * 4 + r] = anchor[row];
        }

    const int swz = (lo16 & 7) << 4;
    unsigned aloff[2], boff[2];
    #pragma unroll
    for (int kk = 0; kk < 2; ++kk) {
        const int cA = (kk * 64 + lg * 16) ^ swz;
        aloff[kk] = (unsigned)((wr * 64 + lo16) * 128 + cA);
        boff[kk] = (unsigned)(32768 + (wc * 64 + lo16) * 128 + cA);
    }
    const int srow = w * 32 + (l >> 3);
    const int scol = ((l & 7) ^ (l >> 3)) << 3;
    const unsigned short* gsrc = XS + (size_t)srow * 256 + scol;

    // A_hi fragments -> registers (bytes identical to swizzled LDS path)
    short8 aH[2][2][4];
    #pragma unroll
    for (int p = 0; p < 2; ++p)
        #pragma unroll
        for (int kk = 0; kk < 2; ++kk)
            #pragma unroll
            for (int mi = 0; mi < 4; ++mi)
                aH[p][kk][mi] = *(const short8*)(
                    XS + (size_t)(ibase + wr * 64 + mi * 16 + lo16) * 256 + p * 64 + kk * 32 + lg * 8);

    auto STAGE_ALO = [&](int kpan, int dstOff) {   // 16KB: 128 rows x 64 shorts
        const unsigned short* g = gsrc + (size_t)ibase * 256 + kpan;
        char* d = smem + dstOff + w * 4096;
        #pragma unroll
        for (int q = 0; q < 4; ++q)
            gload_lds16(g + (size_t)q * 8 * 256, d + q * 1024);
    };
    auto STAGE_B = [&](int jbase, int kpan, int par) {
        const unsigned short* g = gsrc + (size_t)jbase * 256 + kpan;
        char* d = smem + 32768 + par * 16384 + w * 4096;
        #pragma unroll
        for (int q = 0; q < 4; ++q)
            gload_lds16(g + (size_t)q * 8 * 256, d + q * 1024);
    };

    int cnt16[16];
    #pragma unroll
    for (int c = 0; c < 16; ++c) cnt16[c] = 0;

    STAGE_ALO(128, 0);
    STAGE_ALO(192, 16384);
    STAGE_B(jg0, 0, 0);
    __syncthreads();

    #pragma unroll 1
    for (int jt = 0; jt < NJT; ++jt) {
        const int jbase = jg0 + jt * 128;
        float sqj[4];
        #pragma unroll
        for (int ni = 0; ni < 4; ++ni)
            sqj[ni] = sq[jbase + wc * 64 + ni * 16 + lo16];

        f32x4 acc[4][4];
        f32x4 zz = {0.0f, 0.0f, 0.0f, 0.0f};
        #pragma unroll
        for (int mi = 0; mi < 4; ++mi)
            #pragma unroll
            for (int ni = 0; ni < 4; ++ni) acc[mi][ni] = zz;

        #pragma unroll
        for (int s = 0; s < 4; ++s) {
            const int par = s & 1;
            if (s < 3) STAGE_B(jbase, Bpan_[s + 1], par ^ 1);
            else if (jt < NJT - 1) STAGE_B(jbase + 128, 0, par ^ 1);

            const int p = s & 1;   // A_hi panel: s0->0, s1->1, s2->0, s3->1
            #pragma unroll
            for (int kk = 0; kk < 2; ++kk) {
                short8 bF[4];
                #pragma unroll
                for (int ni = 0; ni < 4; ++ni)
                    bF[ni] = *(const short8*)(smem + boff[kk] + par * 16384 + ni * 2048);
                #pragma unroll
                for (int mi = 0; mi < 4; ++mi)
                    #pragma unroll
                    for (int ni = 0; ni < 4; ++ni)
                        acc[mi][ni] = __builtin_amdgcn_mfma_f32_16x16x32_bf16(
                            aH[p][kk][mi], bF[ni], acc[mi][ni], 0, 0, 0);
            }
            if (s < 2) {   // A_lo chain (panel s) on same B
                #pragma unroll
                for (int kk = 0; kk < 2; ++kk) {
                    short8 bF[4], aL[4];
                    #pragma unroll
                    for (int ni = 0; ni < 4; ++ni)
                        bF[ni] = *(const short8*)(smem + boff[kk] + par * 16384 + ni * 2048);
                    #pragma unroll
                    for (int mi = 0; mi < 4; ++mi)
                        aL[mi] = *(const short8*)(smem + s * 16384 + aloff[kk] + mi * 2048);
                    #pragma unroll
                    for (int mi = 0; mi < 4; ++mi)
                        #pragma unroll
                        for (int ni = 0; ni < 4; ++ni)
                            acc[mi][ni] = __builtin_amdgcn_mfma_f32_16x16x32_bf16(
                                aL[mi], bF[ni], acc[mi][ni], 0, 0, 0);
                }
            }
            if (s == 3) {
                #pragma unroll
                for (int mi = 0; mi < 4; ++mi)
                    #pragma unroll
                    for (int r = 0; r < 4; ++r) {
                        const int idx = mi * 4 + r;
                        int c = 0;
                        #pragma unroll
                        for (int ni = 0; ni < 4; ++ni) {
                            float d2 = fmaf(-2.0f, acc[mi][ni][r], sqi[idx] + sqj[ni]);
                            d2 = fmaxf(d2, 0.0f);
                            c += (d2 <= anc[idx]) ? 1 : 0;
                        }
                        cnt16[idx] += c;
                    }
            }
            __syncthreads();
        }
    }

    int* scri = (int*)smem;  // [128][2] (A_lo region dead)
    #pragma unroll
    for (int idx = 0; idx < 16; ++idx) {
        int c = cnt16[idx];
        c += __shfl_xor(c, 1); c += __shfl_xor(c, 2);
        c += __shfl_xor(c, 4); c += __shfl_xor(c, 8);
        if (lo16 == 0) {
            int rl = wr * 64 + (idx >> 2) * 16 + lg * 4 + (idx & 3);
            scri[rl * 2 + wc] = c;
        }
    }
    __syncthreads();
    if (t < 128) cntp[(size_t)(ibase + t) * NJG + jg] = scri[t * 2] + scri[t * 2 + 1];
}

__global__ void reduce_kernel(const int* __restrict__ cntp, float* __restrict__ partials) {
    __shared__ float red[256];
    int t = threadIdx.x;
    int row = blockIdx.x * 256 + t;
    int s = 0;
    for (int c = 0; c < NJG; ++c) s += cntp[(size_t)row * NJG + c];
    red[t] = digammaf_dev((float)(s - 1));
    __syncthreads();
    for (int h = 128; h > 0; h >>= 1) {
        if (t < h) red[t] += red[t + h];
        __syncthreads();
    }
    if (t == 0) partials[blockIdx.x] = red[0];
}

__global__ void finalize_kernel(const float* __restrict__ partials, const int* __restrict__ cls,
                                float* __restrict__ out) {
    if (threadIdx.x == 0) {
        float acc = 0.0f;
        for (int c = 0; c < NTOT / 256; ++c) acc += partials[c];
        float Nf = (float)NTOT;
        float avg_m = acc / Nf;
        float avgNx = 0.0f;
        for (int c = 0; c < NCLS; ++c) {
            float nx = (float)cls[c];
            if (nx > 0.0f) avgNx += (nx / Nf) * digammaf_dev(nx);
        }
        float mi = digammaf_dev(Nf) - avgNx + digammaf_dev(3.0f) - avg_m;
        out[0] = fmaxf(mi / logf(2.0f), 0.0f);
    }
}

extern "C" void kernel_launch(void* const* d_in, const int* in_sizes, int n_in,
                              void* d_out, int out_size, void* d_ws, size_t ws_size,
                              hipStream_t stream) {
    const float* X = (const float*)d_in[0];
    const int* y = (const int*)d_in[1];
    float* out = (float*)d_out;

    float* sq       = (float*)d_ws;                                   // 8192
    float* anchors  = sq + NTOT;                                      // 8192
    float* partials = anchors + NTOT;                                 // 32
    int*   cls      = (int*)(partials + 32);                          // 16
    int*   bcnt     = cls + 16;                                       // 320 (layout keep)
    int*   sOff     = bcnt + 320;                                     // 320
    int*   plan     = sOff + 320;                                     // 48
    int*   yP       = plan + 48;                                      // 9472
    int*   idxP     = yP + NPMAX;                                     // 9472
    float* sqP      = (float*)(idxP + NPMAX);                         // 9472
    unsigned short* XS  = (unsigned short*)(sqP + NPMAX);             // 8192*256 (4 MB)
    unsigned short* XSP = XS + (size_t)NTOT * 256;                    // 9472*256 (4.85 MB)
    float* top4pP   = (float*)(XSP + (size_t)NPMAX * 256);            // 9472*32*4 (4.85 MB)
    int*   cntp     = (int*)(top4pP + (size_t)NPMAX * MAXSLOT * 4);   // 8192*8

    prep_kernel<<<NTOT / 4, 256, 0, stream>>>(X, sq, XS);
    plan_kernel<<<1, 256, 0, stream>>>(y, plan, sOff, cls, yP);
    scatter_kernel<<<NTOT / 256, 256, 0, stream>>>(y, sq, XS, sOff, XSP, sqP, yP, idxP);
    pass1_kernel<<<G1, 256, 0, stream>>>(XSP, yP, sqP, plan, top4pP);
    anchorP_kernel<<<NPMAX / 256, 256, 0, stream>>>(top4pP, yP, idxP, plan, anchors);
    pass2_kernel<<<NTIL * NJG, 256, 0, stream>>>(XS, sq, anchors, cntp);
    reduce_kernel<<<NTOT / 256, 256, 0, stream>>>(cntp, partials);
    finalize_kernel<<<1, 64, 0, stream>>>(partials, cls, out);
}

// Round 19
// 126.001 us; speedup vs baseline: 1.0209x; 1.0209x over previous
//
#include <hip/hip_runtime.h>
#include <hip/hip_bf16.h>
#include <math.h>

#define NCLS 10
#define NTOT 8192
#define NTIL 64                    // 128-row panels per side
#define NJT 8                      // pass-2 j-tiles per block
#define NJG (NTOT / (128 * NJT))   // 8
#define NPMAX 9472                 // padded permuted rows upper bound
#define MAXSLOT 32                 // pass-1 top4 slots per row
#define G1 2048                    // pass-1 grid upper bound (early-exit; plan[40] <= ~1280)

using short8 = __attribute__((ext_vector_type(8))) short;
using f32x4  = __attribute__((ext_vector_type(4))) float;

__device__ __forceinline__ float digammaf_dev(float x) {
    float r = 0.0f;
    while (x < 6.0f) { r -= 1.0f / x; x += 1.0f; }
    float inv = 1.0f / x;
    float inv2 = inv * inv;
    float s = logf(x) - 0.5f * inv
            - inv2 * (0.083333333333f - inv2 * (0.0083333333333f - inv2 * 0.0039682539683f));
    return r + s;
}

__device__ __forceinline__ void cmpswap(float& a, float& b) {
    float lo = fminf(a, b), hi = fmaxf(a, b);
    a = lo; b = hi;
}

__device__ __forceinline__ void ins7(float v, float& b0, float& b1, float& b2, float& b3) {
    float x0 = fminf(b0, v); float c0 = fmaxf(b0, v);
    float x1 = fminf(b1, c0); float c1 = fmaxf(b1, c0);
    float x2 = fminf(b2, c1); float c2 = fmaxf(b2, c1);
    float x3 = fminf(b3, c2);
    b0 = x0; b1 = x1; b2 = x2; b3 = x3;
}

__device__ __forceinline__ void bmerge(int mk, float& v0, float& v1, float& v2, float& v3) {
    float u0 = __shfl_xor(v0, mk), u1 = __shfl_xor(v1, mk);
    float u2 = __shfl_xor(v2, mk), u3 = __shfl_xor(v3, mk);
    float m0 = fminf(v0, u3), m1 = fminf(v1, u2);
    float m2 = fminf(v2, u1), m3 = fminf(v3, u0);
    cmpswap(m0, m2); cmpswap(m1, m3);
    cmpswap(m0, m1); cmpswap(m2, m3);
    v0 = m0; v1 = m1; v2 = m2; v3 = m3;
}

__device__ __forceinline__ void gload_lds16(const void* g, void* s) {
    __builtin_amdgcn_global_load_lds((const __attribute__((address_space(1))) void*)g,
                                     (__attribute__((address_space(3))) void*)s, 16, 0, 0);
}

// per row: sq (fp32), XS[row][0..127]=hi(bf16), [128..255]=lo(bf16)
__global__ void prep_kernel(const float* __restrict__ X,
                            float* __restrict__ sq, unsigned short* __restrict__ XS) {
    int wave = threadIdx.x >> 6, lane = threadIdx.x & 63;
    int row = blockIdx.x * 4 + wave;
    float2 v = *(const float2*)(X + (size_t)row * 128 + lane * 2);
    __hip_bfloat16 h0 = __float2bfloat16(v.x);
    __hip_bfloat16 h1 = __float2bfloat16(v.y);
    float hf0 = __bfloat162float(h0), hf1 = __bfloat162float(h1);
    __hip_bfloat16 l0 = __float2bfloat16(v.x - hf0);
    __hip_bfloat16 l1 = __float2bfloat16(v.y - hf1);
    ushort2 hp, lp;
    hp.x = *(unsigned short*)&h0; hp.y = *(unsigned short*)&h1;
    lp.x = *(unsigned short*)&l0; lp.y = *(unsigned short*)&l1;
    *(ushort2*)(XS + (size_t)row * 256 + lane * 2) = hp;
    *(ushort2*)(XS + (size_t)row * 256 + 128 + lane * 2) = lp;
    float s = fmaf(v.x, v.x, v.y * v.y);
    #pragma unroll
    for (int off = 32; off > 0; off >>= 1) s += __shfl_down(s, off);
    if (lane == 0) sq[row] = s;
}

// plan (1 block, 256 thr): fused histogram (per-256-row chunk via LDS atomics)
// + class prefix + scatter offsets + yP padding init. plan[c]=rowBase,
// [10+c]=T, [20+c]=nsl(=T), [30+c]=cumBlk (2*T*T per class), [40]=nBlocks.
__global__ void plan_kernel(const int* __restrict__ y, int* __restrict__ plan,
                            int* __restrict__ sOff, int* __restrict__ cls,
                            int* __restrict__ yP) {
    __shared__ int hist[32][NCLS];
    __shared__ int sT[NCLS], sBase[NCLS];
    const int t = threadIdx.x;
    for (int i = t; i < 32 * NCLS; i += 256) (&hist[0][0])[i] = 0;
    for (int i = t; i < NPMAX; i += 256) yP[i] = -1;
    __syncthreads();
    {
        const int base = t * 32;         // thread covers rows [t*32, t*32+32)
        const int chunk = t >> 3;        // 8 threads per 256-row chunk
        #pragma unroll 8
        for (int k = 0; k < 32; ++k)
            atomicAdd(&hist[chunk][y[base + k]], 1);
    }
    __syncthreads();
    if (t < NCLS) {
        int run = 0;
        #pragma unroll 8
        for (int b = 0; b < 32; ++b) {
            sOff[b * NCLS + t] = run;    // local prefix; rowBase added below
            run += hist[b][t];
        }
        cls[t] = run;
        sT[t] = (run + 127) >> 7;
    }
    __syncthreads();
    if (t == 0) {
        int rowBase = 0, cum = 0;
        for (int q = 0; q < NCLS; ++q) {
            int T = sT[q];
            sBase[q] = rowBase;
            plan[q] = rowBase;
            plan[10 + q] = T;
            plan[20 + q] = T;
            plan[30 + q] = cum;
            rowBase += T << 7;
            cum += 2 * T * T;
        }
        plan[40] = cum;
    }
    __syncthreads();
    if (t < NCLS) {
        int rb = sBase[t];
        #pragma unroll 8
        for (int b = 0; b < 32; ++b) sOff[b * NCLS + t] += rb;
    }
}

// deterministic class-bucketed scatter: XS -> XSP (+ sqP, yP, idxP)
__global__ void scatter_kernel(const int* __restrict__ y, const float* __restrict__ sq,
                               const unsigned short* __restrict__ XS,
                               const int* __restrict__ sOff,
                               unsigned short* __restrict__ XSP, float* __restrict__ sqP,
                               int* __restrict__ yP, int* __restrict__ idxP) {
    __shared__ int yloc[256];
    __shared__ int dstloc[256];
    const int b = blockIdx.x, t = threadIdx.x;
    const int gid = b * 256 + t;
    const int yv = y[gid];
    yloc[t] = yv;
    __syncthreads();
    int rank = 0;
    for (int k = 0; k < 256; ++k) rank += (k < t && yloc[k] == yv) ? 1 : 0;
    const int dst = sOff[b * NCLS + yv] + rank;
    dstloc[t] = dst;
    sqP[dst] = sq[gid];
    yP[dst] = yv;
    idxP[dst] = gid;
    __syncthreads();
    const int w = t >> 6, l = t & 63;
    for (int r = w; r < 256; r += 4) {
        int d = dstloc[r];
        *(ushort4*)(XSP + (size_t)d * 256 + l * 4) =
            *(const ushort4*)(XS + (size_t)(b * 256 + r) * 256 + l * 4);
    }
}

// Pass 1 (class-bucketed, 64x128 tiles): block -> (class c, i-half, j-tile).
// One tile per block, ~980 blocks, 48KB LDS -> 3 blocks/CU co-resident.
// d2 chain bit-identical to pass 2 (same panel order + fragment mapping).
__global__ __launch_bounds__(256, 2)
void pass1_kernel(const unsigned short* __restrict__ XSP, const int* __restrict__ yP,
                  const float* __restrict__ sqP, const int* __restrict__ plan,
                  float* __restrict__ top4pP) {
    const int bid = blockIdx.x;
    if (bid >= plan[40]) return;
    __shared__ __align__(16) char smem[49152];   // A dbuf 2x8K @0; B dbuf 2x16K @16384

    const int t = threadIdx.x;
    const int w = t >> 6, l = t & 63;
    const int wr = w >> 1, wc = w & 1;
    const int lg = l >> 4, lo16 = l & 15;

    int cc = 0;
    #pragma unroll
    for (int q = 1; q < NCLS; ++q) if (bid >= plan[30 + q]) cc = q;
    const int rowBase = plan[cc], T = plan[10 + cc];
    const int local = bid - plan[30 + cc];
    const int jt = local % T;
    const int itile2 = local / T;
    const int ibase = rowBase + (itile2 >> 1) * 128 + (itile2 & 1) * 64;
    const int jbase = rowBase + jt * 128;

    float sqi[8]; int yi[8];
    #pragma unroll
    for (int mi = 0; mi < 2; ++mi)
        #pragma unroll
        for (int r = 0; r < 4; ++r) {
            int row = ibase + wr * 32 + mi * 16 + lg * 4 + r;
            sqi[mi * 4 + r] = sqP[row];
            yi[mi * 4 + r] = yP[row];
        }
    float sqj[4]; int yj[4];
    #pragma unroll
    for (int ni = 0; ni < 4; ++ni) {
        int col = jbase + wc * 64 + ni * 16 + lo16;
        sqj[ni] = sqP[col];
        yj[ni] = yP[col];
    }

    const int swz = (lo16 & 7) << 4;
    unsigned aoff[2], boff[2];
    #pragma unroll
    for (int kk = 0; kk < 2; ++kk) {
        const int cA = (kk * 64 + lg * 16) ^ swz;
        aoff[kk] = (unsigned)((wr * 32 + lo16) * 128 + cA);
        boff[kk] = (unsigned)(16384 + (wc * 64 + lo16) * 128 + cA);
    }
    const int scol = ((t & 7) ^ ((t >> 3) & 7)) << 3;
    const int srow = t >> 3;   // 0..31

    auto STAGE = [&](int ks, int par) {
        if (ks < 2 || ks >= 4) {
            const int kA = (ks < 4) ? (ks & 1) * 64 : (ks - 2) * 64;
            const unsigned short* gA = XSP + (size_t)(ibase + srow) * 256 + kA + scol;
            char* dA = smem + par * 8192 + t * 16;
            gload_lds16(gA, dA);
            gload_lds16(gA + 32 * 256, dA + 4096);
        }
        const int kB = (ks < 4) ? ks * 64 : (ks - 4) * 64;
        const unsigned short* gB = XSP + (size_t)(jbase + srow) * 256 + kB + scol;
        char* dB = smem + 16384 + par * 16384 + t * 16;
        gload_lds16(gB, dB);
        gload_lds16(gB + 32 * 256, dB + 4096);
        gload_lds16(gB + 64 * 256, dB + 8192);
        gload_lds16(gB + 96 * 256, dB + 12288);
    };

    float tp0[8], tp1[8], tp2[8], tp3[8];
    #pragma unroll
    for (int c = 0; c < 8; ++c) {
        tp0[c] = 1e30f; tp1[c] = 1e30f; tp2[c] = 1e30f; tp3[c] = 1e30f;
    }

    f32x4 acc[2][4];
    f32x4 zz = {0.0f, 0.0f, 0.0f, 0.0f};
    #pragma unroll
    for (int mi = 0; mi < 2; ++mi)
        #pragma unroll
        for (int ni = 0; ni < 4; ++ni) acc[mi][ni] = zz;

    STAGE(0, 0);
    __syncthreads();

    #pragma unroll
    for (int ks = 0; ks < 6; ++ks) {
        const int par = ks & 1;
        if (ks < 5) STAGE(ks + 1, par ^ 1);
        #pragma unroll
        for (int kk = 0; kk < 2; ++kk) {
            short8 aF[2], bF[4];
            #pragma unroll
            for (int mi = 0; mi < 2; ++mi)
                aF[mi] = *(const short8*)(smem + aoff[kk] + par * 8192 + mi * 2048);
            #pragma unroll
            for (int ni = 0; ni < 4; ++ni)
                bF[ni] = *(const short8*)(smem + boff[kk] + par * 16384 + ni * 2048);
            #pragma unroll
            for (int mi = 0; mi < 2; ++mi)
                #pragma unroll
                for (int ni = 0; ni < 4; ++ni)
                    acc[mi][ni] = __builtin_amdgcn_mfma_f32_16x16x32_bf16(
                        aF[mi], bF[ni], acc[mi][ni], 0, 0, 0);
        }
        if (ks == 5) {
            #pragma unroll
            for (int mi = 0; mi < 2; ++mi)
                #pragma unroll
                for (int r = 0; r < 4; ++r) {
                    const int idx = mi * 4 + r;
                    #pragma unroll
                    for (int ni = 0; ni < 4; ++ni) {
                        float d2 = fmaf(-2.0f, acc[mi][ni][r], sqi[idx] + sqj[ni]);
                        d2 = fmaxf(d2, 0.0f);
                        float v = (yi[idx] == yj[ni]) ? d2 : 1e30f;
                        ins7(v, tp0[idx], tp1[idx], tp2[idx], tp3[idx]);
                    }
                }
        }
        __syncthreads();
    }

    // cross-lane + cross-wave merge -> slot jt
    float* scrR = (float*)smem;   // [64 rows][2 wc][4]
    #pragma unroll
    for (int idx = 0; idx < 8; ++idx) {
        float v0 = tp0[idx], v1 = tp1[idx], v2 = tp2[idx], v3 = tp3[idx];
        bmerge(1, v0, v1, v2, v3); bmerge(2, v0, v1, v2, v3);
        bmerge(4, v0, v1, v2, v3); bmerge(8, v0, v1, v2, v3);
        if (lo16 == 0) {
            int rl = wr * 32 + (idx >> 2) * 16 + lg * 4 + (idx & 3);
            float4 st; st.x = v0; st.y = v1; st.z = v2; st.w = v3;
            *(float4*)(scrR + rl * 8 + wc * 4) = st;
        }
    }
    __syncthreads();
    if (t < 64) {
        float4 qa = *(float4*)(scrR + t * 8);
        float4 qb = *(float4*)(scrR + t * 8 + 4);
        float b0 = qa.x, b1 = qa.y, b2 = qa.z, b3 = qa.w;
        ins7(qb.x, b0, b1, b2, b3); ins7(qb.y, b0, b1, b2, b3);
        ins7(qb.z, b0, b1, b2, b3); ins7(qb.w, b0, b1, b2, b3);
        size_t base = ((size_t)(ibase + t) * MAXSLOT + jt) * 4;
        top4pP[base + 0] = b0; top4pP[base + 1] = b1;
        top4pP[base + 2] = b2; top4pP[base + 3] = b3;
    }
}

// merge pass-1 slots -> anchor (scattered back to original index)
__global__ void anchorP_kernel(const float* __restrict__ top4pP, const int* __restrict__ yP,
                               const int* __restrict__ idxP, const int* __restrict__ plan,
                               float* __restrict__ anchor) {
    int r = blockIdx.x * 256 + threadIdx.x;
    int yv = yP[r];
    if (yv < 0) return;
    int nsl = plan[20 + yv];
    float b0 = 1e30f, b1 = 1e30f, b2 = 1e30f, b3 = 1e30f;
    const float4* q4 = (const float4*)(top4pP + (size_t)r * MAXSLOT * 4);
    for (int s = 0; s < nsl; ++s) {
        float4 q = q4[s];
        ins7(q.x, b0, b1, b2, b3); ins7(q.y, b0, b1, b2, b3);
        ins7(q.z, b0, b1, b2, b3); ins7(q.w, b0, b1, b2, b3);
    }
    anchor[idxP[r]] = b3;
}

// Pass 2: FULL-SQUARE count (round-4/12 engine, proven 57.4 us / MfmaUtil 37%).
// Row-side counts only so every pair uses orientation A=i — bit-consistent
// with pass-1's anchors.
__global__ __launch_bounds__(256, 2)
void pass2_kernel(const unsigned short* __restrict__ XS, const float* __restrict__ sq,
                  const float* __restrict__ anchor, int* __restrict__ cntp) {
    __shared__ __align__(16) char smem[65536];

    const int t = threadIdx.x;
    const int w = t >> 6, l = t & 63;
    const int wr = w >> 1, wc = w & 1;
    const int lg = l >> 4, lo16 = l & 15;

    // XCD-aware bijective swizzle (512 % 8 == 0)
    const int bid = blockIdx.x;
    const int wg = (bid & 7) * ((NTIL * NJG) >> 3) + (bid >> 3);
    const int it = wg % NTIL, jg = wg / NTIL;
    const int ibase = it * 128;
    const int jg0 = jg * (128 * NJT);

    float sqi[16]; float anc[16];
    #pragma unroll
    for (int mi = 0; mi < 4; ++mi)
        #pragma unroll
        for (int r = 0; r < 4; ++r) {
            int row = ibase + wr * 64 + mi * 16 + lg * 4 + r;
            sqi[mi * 4 + r] = sq[row];
            anc[mi * 4 + r] = anchor[row];
        }

    const int swz = (lo16 & 7) << 4;
    unsigned aoff[2], boff[2];
    #pragma unroll
    for (int kk = 0; kk < 2; ++kk) {
        const int cA = (kk * 64 + lg * 16) ^ swz;
        aoff[kk] = (unsigned)((wr * 64 + lo16) * 128 + cA);
        boff[kk] = (unsigned)(32768 + (wc * 64 + lo16) * 128 + cA);
    }
    const int srow = w * 32 + (l >> 3);
    const int scol = ((l & 7) ^ (l >> 3)) << 3;
    const unsigned short* gsrc = XS + (size_t)srow * 256 + scol;

    auto STAGE = [&](int jbase_rows, int ks, int par) {
        if (ks < 2 || ks >= 4) {
            const int kA = (ks < 4) ? (ks & 1) * 64 : (ks - 2) * 64;
            char* Ab = smem + par * 16384 + w * 4096;
            const unsigned short* gA = gsrc + (size_t)ibase * 256 + kA;
            #pragma unroll
            for (int q = 0; q < 4; ++q)
                gload_lds16(gA + (size_t)q * 8 * 256, Ab + q * 1024);
        }
        const int kB = (ks < 4) ? ks * 64 : (ks - 4) * 64;
        char* Bb = smem + 32768 + par * 16384 + w * 4096;
        const unsigned short* gB = gsrc + (size_t)jbase_rows * 256 + kB;
        #pragma unroll
        for (int q = 0; q < 4; ++q)
            gload_lds16(gB + (size_t)q * 8 * 256, Bb + q * 1024);
    };

    int cnt16[16];
    #pragma unroll
    for (int c = 0; c < 16; ++c) cnt16[c] = 0;

    STAGE(jg0, 0, 0);
    __syncthreads();

    #pragma unroll 1
    for (int jt = 0; jt < NJT; ++jt) {
        const int jbase = jg0 + jt * 128;
        float sqj[4];
        #pragma unroll
        for (int ni = 0; ni < 4; ++ni)
            sqj[ni] = sq[jbase + wc * 64 + ni * 16 + lo16];

        f32x4 acc[4][4];
        f32x4 zz = {0.0f, 0.0f, 0.0f, 0.0f};
        #pragma unroll
        for (int mi = 0; mi < 4; ++mi)
            #pragma unroll
            for (int ni = 0; ni < 4; ++ni) acc[mi][ni] = zz;

        #pragma unroll
        for (int ks = 0; ks < 6; ++ks) {
            const int par = ks & 1;
            if (ks < 5) STAGE(jbase, ks + 1, par ^ 1);
            else if (jt < NJT - 1) STAGE(jbase + 128, 0, par ^ 1);

            #pragma unroll
            for (int kk = 0; kk < 2; ++kk) {
                short8 aF[4], bF[4];
                #pragma unroll
                for (int mi = 0; mi < 4; ++mi)
                    aF[mi] = *(const short8*)(smem + aoff[kk] + par * 16384 + mi * 2048);
                #pragma unroll
                for (int ni = 0; ni < 4; ++ni)
                    bF[ni] = *(const short8*)(smem + boff[kk] + par * 16384 + ni * 2048);
                #pragma unroll
                for (int mi = 0; mi < 4; ++mi)
                    #pragma unroll
                    for (int ni = 0; ni < 4; ++ni)
                        acc[mi][ni] = __builtin_amdgcn_mfma_f32_16x16x32_bf16(
                            aF[mi], bF[ni], acc[mi][ni], 0, 0, 0);
            }

            if (ks == 5) {
                #pragma unroll
                for (int mi = 0; mi < 4; ++mi)
                    #pragma unroll
                    for (int r = 0; r < 4; ++r) {
                        const int idx = mi * 4 + r;
                        int c = 0;
                        #pragma unroll
                        for (int ni = 0; ni < 4; ++ni) {
                            float d2 = fmaf(-2.0f, acc[mi][ni][r], sqi[idx] + sqj[ni]);
                            d2 = fmaxf(d2, 0.0f);
                            c += (d2 <= anc[idx]) ? 1 : 0;
                        }
                        cnt16[idx] += c;
                    }
            }
            __syncthreads();
        }
    }

    int* scri = (int*)smem;  // [128][2]
    #pragma unroll
    for (int idx = 0; idx < 16; ++idx) {
        int c = cnt16[idx];
        c += __shfl_xor(c, 1); c += __shfl_xor(c, 2);
        c += __shfl_xor(c, 4); c += __shfl_xor(c, 8);
        if (lo16 == 0) {
            int rl = wr * 64 + (idx >> 2) * 16 + lg * 4 + (idx & 3);
            scri[rl * 2 + wc] = c;
        }
    }
    __syncthreads();
    if (t < 128) cntp[(size_t)(ibase + t) * NJG + jg] = scri[t * 2] + scri[t * 2 + 1];
}

__global__ void reduce_kernel(const int* __restrict__ cntp, float* __restrict__ partials) {
    __shared__ float red[256];
    int t = threadIdx.x;
    int row = blockIdx.x * 256 + t;
    int s = 0;
    for (int c = 0; c < NJG; ++c) s += cntp[(size_t)row * NJG + c];
    red[t] = digammaf_dev((float)(s - 1));
    __syncthreads();
    for (int h = 128; h > 0; h >>= 1) {
        if (t < h) red[t] += red[t + h];
        __syncthreads();
    }
    if (t == 0) partials[blockIdx.x] = red[0];
}

__global__ void finalize_kernel(const float* __restrict__ partials, const int* __restrict__ cls,
                                float* __restrict__ out) {
    if (threadIdx.x == 0) {
        float acc = 0.0f;
        for (int c = 0; c < NTOT / 256; ++c) acc += partials[c];
        float Nf = (float)NTOT;
        float avg_m = acc / Nf;
        float avgNx = 0.0f;
        for (int c = 0; c < NCLS; ++c) {
            float nx = (float)cls[c];
            if (nx > 0.0f) avgNx += (nx / Nf) * digammaf_dev(nx);
        }
        float mi = digammaf_dev(Nf) - avgNx + digammaf_dev(3.0f) - avg_m;
        out[0] = fmaxf(mi / logf(2.0f), 0.0f);
    }
}

extern "C" void kernel_launch(void* const* d_in, const int* in_sizes, int n_in,
                              void* d_out, int out_size, void* d_ws, size_t ws_size,
                              hipStream_t stream) {
    const float* X = (const float*)d_in[0];
    const int* y = (const int*)d_in[1];
    float* out = (float*)d_out;

    float* sq       = (float*)d_ws;                                   // 8192
    float* anchors  = sq + NTOT;                                      // 8192
    float* partials = anchors + NTOT;                                 // 32
    int*   cls      = (int*)(partials + 32);                          // 16
    int*   bcnt     = cls + 16;                                       // 320 (layout keep)
    int*   sOff     = bcnt + 320;                                     // 320
    int*   plan     = sOff + 320;                                     // 48
    int*   yP       = plan + 48;                                      // 9472
    int*   idxP     = yP + NPMAX;                                     // 9472
    float* sqP      = (float*)(idxP + NPMAX);                         // 9472
    unsigned short* XS  = (unsigned short*)(sqP + NPMAX);             // 8192*256 (4 MB)
    unsigned short* XSP = XS + (size_t)NTOT * 256;                    // 9472*256 (4.85 MB)
    float* top4pP   = (float*)(XSP + (size_t)NPMAX * 256);            // 9472*32*4 (4.85 MB)
    int*   cntp     = (int*)(top4pP + (size_t)NPMAX * MAXSLOT * 4);   // 8192*8

    prep_kernel<<<NTOT / 4, 256, 0, stream>>>(X, sq, XS);
    plan_kernel<<<1, 256, 0, stream>>>(y, plan, sOff, cls, yP);
    scatter_kernel<<<NTOT / 256, 256, 0, stream>>>(y, sq, XS, sOff, XSP, sqP, yP, idxP);
    pass1_kernel<<<G1, 256, 0, stream>>>(XSP, yP, sqP, plan, top4pP);
    anchorP_kernel<<<NPMAX / 256, 256, 0, stream>>>(top4pP, yP, idxP, plan, anchors);
    pass2_kernel<<<NTIL * NJG, 256, 0, stream>>>(XS, sq, anchors, cntp);
    reduce_kernel<<<NTOT / 256, 256, 0, stream>>>(cntp, partials);
    finalize_kernel<<<1, 64, 0, stream>>>(partials, cls, out);
}

// Round 20
// 122.772 us; speedup vs baseline: 1.0478x; 1.0263x over previous
//
#include <hip/hip_runtime.h>
#include <hip/hip_bf16.h>
#include <math.h>

#define NCLS 10
#define NTOT 8192
#define NTIL 64                    // 128-row panels per side
#define NJT 8                      // pass-2 j-tiles per block
#define NJG (NTOT / (128 * NJT))   // 8
#define NPMAX 9472                 // padded permuted rows upper bound
#define MAXSLOT 32                 // pass-1 top4 slots per row
#define G1 2048                    // pass-1 grid upper bound (early-exit)

using short8 = __attribute__((ext_vector_type(8))) short;
using f32x4  = __attribute__((ext_vector_type(4))) float;

__device__ __forceinline__ float digammaf_dev(float x) {
    float r = 0.0f;
    while (x < 6.0f) { r -= 1.0f / x; x += 1.0f; }
    float inv = 1.0f / x;
    float inv2 = inv * inv;
    float s = logf(x) - 0.5f * inv
            - inv2 * (0.083333333333f - inv2 * (0.0083333333333f - inv2 * 0.0039682539683f));
    return r + s;
}

__device__ __forceinline__ void cmpswap(float& a, float& b) {
    float lo = fminf(a, b), hi = fmaxf(a, b);
    a = lo; b = hi;
}

__device__ __forceinline__ void ins7(float v, float& b0, float& b1, float& b2, float& b3) {
    float x0 = fminf(b0, v); float c0 = fmaxf(b0, v);
    float x1 = fminf(b1, c0); float c1 = fmaxf(b1, c0);
    float x2 = fminf(b2, c1); float c2 = fmaxf(b2, c1);
    float x3 = fminf(b3, c2);
    b0 = x0; b1 = x1; b2 = x2; b3 = x3;
}

__device__ __forceinline__ void bmerge(int mk, float& v0, float& v1, float& v2, float& v3) {
    float u0 = __shfl_xor(v0, mk), u1 = __shfl_xor(v1, mk);
    float u2 = __shfl_xor(v2, mk), u3 = __shfl_xor(v3, mk);
    float m0 = fminf(v0, u3), m1 = fminf(v1, u2);
    float m2 = fminf(v2, u1), m3 = fminf(v3, u0);
    cmpswap(m0, m2); cmpswap(m1, m3);
    cmpswap(m0, m1); cmpswap(m2, m3);
    v0 = m0; v1 = m1; v2 = m2; v3 = m3;
}

__device__ __forceinline__ void gload_lds16(const void* g, void* s) {
    __builtin_amdgcn_global_load_lds((const __attribute__((address_space(1))) void*)g,
                                     (__attribute__((address_space(3))) void*)s, 16, 0, 0);
}

// Fused prep + plan. Blocks 0..2047: per row sq (fp32) and XS split
// (hi @ [0,128), lo @ [128,256)). Block 2048: histogram+prefix plan,
// sOff scatter bases, cls totals, yP padding init, ticket reset.
__global__ void prep_plan_kernel(const float* __restrict__ X, const int* __restrict__ y,
                                 float* __restrict__ sq, unsigned short* __restrict__ XS,
                                 int* __restrict__ plan, int* __restrict__ sOff,
                                 int* __restrict__ cls, int* __restrict__ yP,
                                 int* __restrict__ ticket) {
    __shared__ int hist[32][NCLS];
    __shared__ int sT[NCLS], sBase[NCLS];
    const int t = threadIdx.x;

    if (blockIdx.x < NTOT / 4) {
        // ---- prep path ----
        int wave = t >> 6, lane = t & 63;
        int row = blockIdx.x * 4 + wave;
        float2 v = *(const float2*)(X + (size_t)row * 128 + lane * 2);
        __hip_bfloat16 h0 = __float2bfloat16(v.x);
        __hip_bfloat16 h1 = __float2bfloat16(v.y);
        float hf0 = __bfloat162float(h0), hf1 = __bfloat162float(h1);
        __hip_bfloat16 l0 = __float2bfloat16(v.x - hf0);
        __hip_bfloat16 l1 = __float2bfloat16(v.y - hf1);
        ushort2 hp, lp;
        hp.x = *(unsigned short*)&h0; hp.y = *(unsigned short*)&h1;
        lp.x = *(unsigned short*)&l0; lp.y = *(unsigned short*)&l1;
        *(ushort2*)(XS + (size_t)row * 256 + lane * 2) = hp;
        *(ushort2*)(XS + (size_t)row * 256 + 128 + lane * 2) = lp;
        float s = fmaf(v.x, v.x, v.y * v.y);
        #pragma unroll
        for (int off = 32; off > 0; off >>= 1) s += __shfl_down(s, off);
        if (lane == 0) sq[row] = s;
        return;
    }

    // ---- plan path (block 2048) ----
    for (int i = t; i < 32 * NCLS; i += 256) (&hist[0][0])[i] = 0;
    for (int i = t; i < NPMAX; i += 256) yP[i] = -1;
    if (t == 0) *ticket = 0;
    __syncthreads();
    {
        const int base = t * 32;
        const int chunk = t >> 3;
        #pragma unroll 8
        for (int k = 0; k < 32; ++k)
            atomicAdd(&hist[chunk][y[base + k]], 1);
    }
    __syncthreads();
    if (t < NCLS) {
        int run = 0;
        #pragma unroll 8
        for (int b = 0; b < 32; ++b) {
            sOff[b * NCLS + t] = run;
            run += hist[b][t];
        }
        cls[t] = run;
        sT[t] = (run + 127) >> 7;
    }
    __syncthreads();
    if (t == 0) {
        int rowBase = 0, cum = 0;
        for (int q = 0; q < NCLS; ++q) {
            int T = sT[q];
            sBase[q] = rowBase;
            plan[q] = rowBase;
            plan[10 + q] = T;
            plan[20 + q] = T;
            plan[30 + q] = cum;
            rowBase += T << 7;
            cum += 2 * T * T;
        }
        plan[40] = cum;
    }
    __syncthreads();
    if (t < NCLS) {
        int rb = sBase[t];
        #pragma unroll 8
        for (int b = 0; b < 32; ++b) sOff[b * NCLS + t] += rb;
    }
}

// deterministic class-bucketed scatter: XS -> XSP (+ sqP, yP, idxP)
__global__ void scatter_kernel(const int* __restrict__ y, const float* __restrict__ sq,
                               const unsigned short* __restrict__ XS,
                               const int* __restrict__ sOff,
                               unsigned short* __restrict__ XSP, float* __restrict__ sqP,
                               int* __restrict__ yP, int* __restrict__ idxP) {
    __shared__ int yloc[256];
    __shared__ int dstloc[256];
    const int b = blockIdx.x, t = threadIdx.x;
    const int gid = b * 256 + t;
    const int yv = y[gid];
    yloc[t] = yv;
    __syncthreads();
    int rank = 0;
    for (int k = 0; k < 256; ++k) rank += (k < t && yloc[k] == yv) ? 1 : 0;
    const int dst = sOff[b * NCLS + yv] + rank;
    dstloc[t] = dst;
    sqP[dst] = sq[gid];
    yP[dst] = yv;
    idxP[dst] = gid;
    __syncthreads();
    const int w = t >> 6, l = t & 63;
    for (int r = w; r < 256; r += 4) {
        int d = dstloc[r];
        *(ushort4*)(XSP + (size_t)d * 256 + l * 4) =
            *(const ushort4*)(XS + (size_t)(b * 256 + r) * 256 + l * 4);
    }
}

// Pass 1 (class-bucketed, 64x128 tiles): block -> (class c, i-half, j-tile).
__global__ __launch_bounds__(256, 2)
void pass1_kernel(const unsigned short* __restrict__ XSP, const int* __restrict__ yP,
                  const float* __restrict__ sqP, const int* __restrict__ plan,
                  float* __restrict__ top4pP) {
    const int bid = blockIdx.x;
    if (bid >= plan[40]) return;
    __shared__ __align__(16) char smem[49152];   // A dbuf 2x8K @0; B dbuf 2x16K @16384

    const int t = threadIdx.x;
    const int w = t >> 6, l = t & 63;
    const int wr = w >> 1, wc = w & 1;
    const int lg = l >> 4, lo16 = l & 15;

    int cc = 0;
    #pragma unroll
    for (int q = 1; q < NCLS; ++q) if (bid >= plan[30 + q]) cc = q;
    const int rowBase = plan[cc], T = plan[10 + cc];
    const int local = bid - plan[30 + cc];
    const int jt = local % T;
    const int itile2 = local / T;
    const int ibase = rowBase + (itile2 >> 1) * 128 + (itile2 & 1) * 64;
    const int jbase = rowBase + jt * 128;

    float sqi[8]; int yi[8];
    #pragma unroll
    for (int mi = 0; mi < 2; ++mi)
        #pragma unroll
        for (int r = 0; r < 4; ++r) {
            int row = ibase + wr * 32 + mi * 16 + lg * 4 + r;
            sqi[mi * 4 + r] = sqP[row];
            yi[mi * 4 + r] = yP[row];
        }
    float sqj[4]; int yj[4];
    #pragma unroll
    for (int ni = 0; ni < 4; ++ni) {
        int col = jbase + wc * 64 + ni * 16 + lo16;
        sqj[ni] = sqP[col];
        yj[ni] = yP[col];
    }

    const int swz = (lo16 & 7) << 4;
    unsigned aoff[2], boff[2];
    #pragma unroll
    for (int kk = 0; kk < 2; ++kk) {
        const int cA = (kk * 64 + lg * 16) ^ swz;
        aoff[kk] = (unsigned)((wr * 32 + lo16) * 128 + cA);
        boff[kk] = (unsigned)(16384 + (wc * 64 + lo16) * 128 + cA);
    }
    const int scol = ((t & 7) ^ ((t >> 3) & 7)) << 3;
    const int srow = t >> 3;   // 0..31

    auto STAGE = [&](int ks, int par) {
        if (ks < 2 || ks >= 4) {
            const int kA = (ks < 4) ? (ks & 1) * 64 : (ks - 2) * 64;
            const unsigned short* gA = XSP + (size_t)(ibase + srow) * 256 + kA + scol;
            char* dA = smem + par * 8192 + t * 16;
            gload_lds16(gA, dA);
            gload_lds16(gA + 32 * 256, dA + 4096);
        }
        const int kB = (ks < 4) ? ks * 64 : (ks - 4) * 64;
        const unsigned short* gB = XSP + (size_t)(jbase + srow) * 256 + kB + scol;
        char* dB = smem + 16384 + par * 16384 + t * 16;
        gload_lds16(gB, dB);
        gload_lds16(gB + 32 * 256, dB + 4096);
        gload_lds16(gB + 64 * 256, dB + 8192);
        gload_lds16(gB + 96 * 256, dB + 12288);
    };

    float tp0[8], tp1[8], tp2[8], tp3[8];
    #pragma unroll
    for (int c = 0; c < 8; ++c) {
        tp0[c] = 1e30f; tp1[c] = 1e30f; tp2[c] = 1e30f; tp3[c] = 1e30f;
    }

    f32x4 acc[2][4];
    f32x4 zz = {0.0f, 0.0f, 0.0f, 0.0f};
    #pragma unroll
    for (int mi = 0; mi < 2; ++mi)
        #pragma unroll
        for (int ni = 0; ni < 4; ++ni) acc[mi][ni] = zz;

    STAGE(0, 0);
    __syncthreads();

    #pragma unroll
    for (int ks = 0; ks < 6; ++ks) {
        const int par = ks & 1;
        if (ks < 5) STAGE(ks + 1, par ^ 1);
        #pragma unroll
        for (int kk = 0; kk < 2; ++kk) {
            short8 aF[2], bF[4];
            #pragma unroll
            for (int mi = 0; mi < 2; ++mi)
                aF[mi] = *(const short8*)(smem + aoff[kk] + par * 8192 + mi * 2048);
            #pragma unroll
            for (int ni = 0; ni < 4; ++ni)
                bF[ni] = *(const short8*)(smem + boff[kk] + par * 16384 + ni * 2048);
            #pragma unroll
            for (int mi = 0; mi < 2; ++mi)
                #pragma unroll
                for (int ni = 0; ni < 4; ++ni)
                    acc[mi][ni] = __builtin_amdgcn_mfma_f32_16x16x32_bf16(
                        aF[mi], bF[ni], acc[mi][ni], 0, 0, 0);
        }
        if (ks == 5) {
            #pragma unroll
            for (int mi = 0; mi < 2; ++mi)
                #pragma unroll
                for (int r = 0; r < 4; ++r) {
                    const int idx = mi * 4 + r;
                    #pragma unroll
                    for (int ni = 0; ni < 4; ++ni) {
                        float d2 = fmaf(-2.0f, acc[mi][ni][r], sqi[idx] + sqj[ni]);
                        d2 = fmaxf(d2, 0.0f);
                        float v = (yi[idx] == yj[ni]) ? d2 : 1e30f;
                        ins7(v, tp0[idx], tp1[idx], tp2[idx], tp3[idx]);
                    }
                }
        }
        __syncthreads();
    }

    // cross-lane + cross-wave merge -> slot jt
    float* scrR = (float*)smem;   // [64 rows][2 wc][4]
    #pragma unroll
    for (int idx = 0; idx < 8; ++idx) {
        float v0 = tp0[idx], v1 = tp1[idx], v2 = tp2[idx], v3 = tp3[idx];
        bmerge(1, v0, v1, v2, v3); bmerge(2, v0, v1, v2, v3);
        bmerge(4, v0, v1, v2, v3); bmerge(8, v0, v1, v2, v3);
        if (lo16 == 0) {
            int rl = wr * 32 + (idx >> 2) * 16 + lg * 4 + (idx & 3);
            float4 st; st.x = v0; st.y = v1; st.z = v2; st.w = v3;
            *(float4*)(scrR + rl * 8 + wc * 4) = st;
        }
    }
    __syncthreads();
    if (t < 64) {
        float4 qa = *(float4*)(scrR + t * 8);
        float4 qb = *(float4*)(scrR + t * 8 + 4);
        float b0 = qa.x, b1 = qa.y, b2 = qa.z, b3 = qa.w;
        ins7(qb.x, b0, b1, b2, b3); ins7(qb.y, b0, b1, b2, b3);
        ins7(qb.z, b0, b1, b2, b3); ins7(qb.w, b0, b1, b2, b3);
        size_t base = ((size_t)(ibase + t) * MAXSLOT + jt) * 4;
        top4pP[base + 0] = b0; top4pP[base + 1] = b1;
        top4pP[base + 2] = b2; top4pP[base + 3] = b3;
    }
}

// merge pass-1 slots -> anchor (scattered back to original index)
__global__ void anchorP_kernel(const float* __restrict__ top4pP, const int* __restrict__ yP,
                               const int* __restrict__ idxP, const int* __restrict__ plan,
                               float* __restrict__ anchor) {
    int r = blockIdx.x * 256 + threadIdx.x;
    int yv = yP[r];
    if (yv < 0) return;
    int nsl = plan[20 + yv];
    float b0 = 1e30f, b1 = 1e30f, b2 = 1e30f, b3 = 1e30f;
    const float4* q4 = (const float4*)(top4pP + (size_t)r * MAXSLOT * 4);
    for (int s = 0; s < nsl; ++s) {
        float4 q = q4[s];
        ins7(q.x, b0, b1, b2, b3); ins7(q.y, b0, b1, b2, b3);
        ins7(q.z, b0, b1, b2, b3); ins7(q.w, b0, b1, b2, b3);
    }
    anchor[idxP[r]] = b3;
}

// Pass 2: FULL-SQUARE count (round-4/12 engine, proven 57.4 us / MfmaUtil 37%).
__global__ __launch_bounds__(256, 2)
void pass2_kernel(const unsigned short* __restrict__ XS, const float* __restrict__ sq,
                  const float* __restrict__ anchor, int* __restrict__ cntp) {
    __shared__ __align__(16) char smem[65536];

    const int t = threadIdx.x;
    const int w = t >> 6, l = t & 63;
    const int wr = w >> 1, wc = w & 1;
    const int lg = l >> 4, lo16 = l & 15;

    const int bid = blockIdx.x;
    const int wg = (bid & 7) * ((NTIL * NJG) >> 3) + (bid >> 3);
    const int it = wg % NTIL, jg = wg / NTIL;
    const int ibase = it * 128;
    const int jg0 = jg * (128 * NJT);

    float sqi[16]; float anc[16];
    #pragma unroll
    for (int mi = 0; mi < 4; ++mi)
        #pragma unroll
        for (int r = 0; r < 4; ++r) {
            int row = ibase + wr * 64 + mi * 16 + lg * 4 + r;
            sqi[mi * 4 + r] = sq[row];
            anc[mi * 4 + r] = anchor[row];
        }

    const int swz = (lo16 & 7) << 4;
    unsigned aoff[2], boff[2];
    #pragma unroll
    for (int kk = 0; kk < 2; ++kk) {
        const int cA = (kk * 64 + lg * 16) ^ swz;
        aoff[kk] = (unsigned)((wr * 64 + lo16) * 128 + cA);
        boff[kk] = (unsigned)(32768 + (wc * 64 + lo16) * 128 + cA);
    }
    const int srow = w * 32 + (l >> 3);
    const int scol = ((l & 7) ^ (l >> 3)) << 3;
    const unsigned short* gsrc = XS + (size_t)srow * 256 + scol;

    auto STAGE = [&](int jbase_rows, int ks, int par) {
        if (ks < 2 || ks >= 4) {
            const int kA = (ks < 4) ? (ks & 1) * 64 : (ks - 2) * 64;
            char* Ab = smem + par * 16384 + w * 4096;
            const unsigned short* gA = gsrc + (size_t)ibase * 256 + kA;
            #pragma unroll
            for (int q = 0; q < 4; ++q)
                gload_lds16(gA + (size_t)q * 8 * 256, Ab + q * 1024);
        }
        const int kB = (ks < 4) ? ks * 64 : (ks - 4) * 64;
        char* Bb = smem + 32768 + par * 16384 + w * 4096;
        const unsigned short* gB = gsrc + (size_t)jbase_rows * 256 + kB;
        #pragma unroll
        for (int q = 0; q < 4; ++q)
            gload_lds16(gB + (size_t)q * 8 * 256, Bb + q * 1024);
    };

    int cnt16[16];
    #pragma unroll
    for (int c = 0; c < 16; ++c) cnt16[c] = 0;

    STAGE(jg0, 0, 0);
    __syncthreads();

    #pragma unroll 1
    for (int jt = 0; jt < NJT; ++jt) {
        const int jbase = jg0 + jt * 128;
        float sqj[4];
        #pragma unroll
        for (int ni = 0; ni < 4; ++ni)
            sqj[ni] = sq[jbase + wc * 64 + ni * 16 + lo16];

        f32x4 acc[4][4];
        f32x4 zz = {0.0f, 0.0f, 0.0f, 0.0f};
        #pragma unroll
        for (int mi = 0; mi < 4; ++mi)
            #pragma unroll
            for (int ni = 0; ni < 4; ++ni) acc[mi][ni] = zz;

        #pragma unroll
        for (int ks = 0; ks < 6; ++ks) {
            const int par = ks & 1;
            if (ks < 5) STAGE(jbase, ks + 1, par ^ 1);
            else if (jt < NJT - 1) STAGE(jbase + 128, 0, par ^ 1);

            #pragma unroll
            for (int kk = 0; kk < 2; ++kk) {
                short8 aF[4], bF[4];
                #pragma unroll
                for (int mi = 0; mi < 4; ++mi)
                    aF[mi] = *(const short8*)(smem + aoff[kk] + par * 16384 + mi * 2048);
                #pragma unroll
                for (int ni = 0; ni < 4; ++ni)
                    bF[ni] = *(const short8*)(smem + boff[kk] + par * 16384 + ni * 2048);
                #pragma unroll
                for (int mi = 0; mi < 4; ++mi)
                    #pragma unroll
                    for (int ni = 0; ni < 4; ++ni)
                        acc[mi][ni] = __builtin_amdgcn_mfma_f32_16x16x32_bf16(
                            aF[mi], bF[ni], acc[mi][ni], 0, 0, 0);
            }

            if (ks == 5) {
                #pragma unroll
                for (int mi = 0; mi < 4; ++mi)
                    #pragma unroll
                    for (int r = 0; r < 4; ++r) {
                        const int idx = mi * 4 + r;
                        int c = 0;
                        #pragma unroll
                        for (int ni = 0; ni < 4; ++ni) {
                            float d2 = fmaf(-2.0f, acc[mi][ni][r], sqi[idx] + sqj[ni]);
                            d2 = fmaxf(d2, 0.0f);
                            c += (d2 <= anc[idx]) ? 1 : 0;
                        }
                        cnt16[idx] += c;
                    }
            }
            __syncthreads();
        }
    }

    int* scri = (int*)smem;  // [128][2]
    #pragma unroll
    for (int idx = 0; idx < 16; ++idx) {
        int c = cnt16[idx];
        c += __shfl_xor(c, 1); c += __shfl_xor(c, 2);
        c += __shfl_xor(c, 4); c += __shfl_xor(c, 8);
        if (lo16 == 0) {
            int rl = wr * 64 + (idx >> 2) * 16 + lg * 4 + (idx & 3);
            scri[rl * 2 + wc] = c;
        }
    }
    __syncthreads();
    if (t < 128) cntp[(size_t)(ibase + t) * NJG + jg] = scri[t * 2] + scri[t * 2 + 1];
}

// Fused reduce + finalize (last-block ticket). Partials written in fixed
// order; last block sums c=0..31 in fixed order -> bit-identical output.
__global__ void reduce_fin_kernel(const int* __restrict__ cntp, const int* __restrict__ cls,
                                  float* __restrict__ partials, int* __restrict__ ticket,
                                  float* __restrict__ out) {
    __shared__ float red[256];
    __shared__ bool last;
    int t = threadIdx.x;
    int row = blockIdx.x * 256 + t;
    int s = 0;
    for (int c = 0; c < NJG; ++c) s += cntp[(size_t)row * NJG + c];
    red[t] = digammaf_dev((float)(s - 1));
    __syncthreads();
    for (int h = 128; h > 0; h >>= 1) {
        if (t < h) red[t] += red[t + h];
        __syncthreads();
    }
    if (t == 0) {
        partials[blockIdx.x] = red[0];
        __threadfence();
        int fin = atomicAdd(ticket, 1);
        last = (fin == (NTOT / 256) - 1);
    }
    __syncthreads();
    if (last && t == 0) {
        __threadfence();
        float acc = 0.0f;
        for (int c = 0; c < NTOT / 256; ++c) acc += partials[c];
        float Nf = (float)NTOT;
        float avg_m = acc / Nf;
        float avgNx = 0.0f;
        for (int c = 0; c < NCLS; ++c) {
            float nx = (float)cls[c];
            if (nx > 0.0f) avgNx += (nx / Nf) * digammaf_dev(nx);
        }
        float mi = digammaf_dev(Nf) - avgNx + digammaf_dev(3.0f) - avg_m;
        out[0] = fmaxf(mi / logf(2.0f), 0.0f);
    }
}

extern "C" void kernel_launch(void* const* d_in, const int* in_sizes, int n_in,
                              void* d_out, int out_size, void* d_ws, size_t ws_size,
                              hipStream_t stream) {
    const float* X = (const float*)d_in[0];
    const int* y = (const int*)d_in[1];
    float* out = (float*)d_out;

    float* sq       = (float*)d_ws;                                   // 8192
    float* anchors  = sq + NTOT;                                      // 8192
    float* partials = anchors + NTOT;                                 // 32
    int*   cls      = (int*)(partials + 32);                          // 16
    int*   ticket   = cls + 16;                                       // 1 (+pad 319)
    int*   sOff     = ticket + 320;                                   // 320
    int*   plan     = sOff + 320;                                     // 48
    int*   yP       = plan + 48;                                      // 9472
    int*   idxP     = yP + NPMAX;                                     // 9472
    float* sqP      = (float*)(idxP + NPMAX);                         // 9472
    unsigned short* XS  = (unsigned short*)(sqP + NPMAX);             // 8192*256 (4 MB)
    unsigned short* XSP = XS + (size_t)NTOT * 256;                    // 9472*256 (4.85 MB)
    float* top4pP   = (float*)(XSP + (size_t)NPMAX * 256);            // 9472*32*4 (4.85 MB)
    int*   cntp     = (int*)(top4pP + (size_t)NPMAX * MAXSLOT * 4);   // 8192*8

    prep_plan_kernel<<<NTOT / 4 + 1, 256, 0, stream>>>(X, y, sq, XS, plan, sOff, cls, yP, ticket);
    scatter_kernel<<<NTOT / 256, 256, 0, stream>>>(y, sq, XS, sOff, XSP, sqP, yP, idxP);
    pass1_kernel<<<G1, 256, 0, stream>>>(XSP, yP, sqP, plan, top4pP);
    anchorP_kernel<<<NPMAX / 256, 256, 0, stream>>>(top4pP, yP, idxP, plan, anchors);
    pass2_kernel<<<NTIL * NJG, 256, 0, stream>>>(XS, sq, anchors, cntp);
    reduce_fin_kernel<<<NTOT / 256, 256, 0, stream>>>(cntp, cls, partials, ticket, out);
}

// Round 21
// 119.801 us; speedup vs baseline: 1.0738x; 1.0248x over previous
//
#include <hip/hip_runtime.h>
#include <hip/hip_bf16.h>
#include <math.h>

#define NCLS 10
#define NTOT 8192
#define NTIL 64                    // 128-row panels per side
#define NJT 8                      // pass-2 j-tiles per block
#define NJG (NTOT / (128 * NJT))   // 8
#define NPMAX 9472                 // padded permuted rows upper bound
#define MAXSLOT 32                 // pass-1 top4 slots per row
#define G1 2048                    // pass-1 grid upper bound (early-exit)

using short8 = __attribute__((ext_vector_type(8))) short;
using f32x4  = __attribute__((ext_vector_type(4))) float;

__device__ __forceinline__ float digammaf_dev(float x) {
    float r = 0.0f;
    while (x < 6.0f) { r -= 1.0f / x; x += 1.0f; }
    float inv = 1.0f / x;
    float inv2 = inv * inv;
    float s = logf(x) - 0.5f * inv
            - inv2 * (0.083333333333f - inv2 * (0.0083333333333f - inv2 * 0.0039682539683f));
    return r + s;
}

__device__ __forceinline__ void cmpswap(float& a, float& b) {
    float lo = fminf(a, b), hi = fmaxf(a, b);
    a = lo; b = hi;
}

__device__ __forceinline__ void ins7(float v, float& b0, float& b1, float& b2, float& b3) {
    float x0 = fminf(b0, v); float c0 = fmaxf(b0, v);
    float x1 = fminf(b1, c0); float c1 = fmaxf(b1, c0);
    float x2 = fminf(b2, c1); float c2 = fmaxf(b2, c1);
    float x3 = fminf(b3, c2);
    b0 = x0; b1 = x1; b2 = x2; b3 = x3;
}

__device__ __forceinline__ void bmerge(int mk, float& v0, float& v1, float& v2, float& v3) {
    float u0 = __shfl_xor(v0, mk), u1 = __shfl_xor(v1, mk);
    float u2 = __shfl_xor(v2, mk), u3 = __shfl_xor(v3, mk);
    float m0 = fminf(v0, u3), m1 = fminf(v1, u2);
    float m2 = fminf(v2, u1), m3 = fminf(v3, u0);
    cmpswap(m0, m2); cmpswap(m1, m3);
    cmpswap(m0, m1); cmpswap(m2, m3);
    v0 = m0; v1 = m1; v2 = m2; v3 = m3;
}

__device__ __forceinline__ void gload_lds16(const void* g, void* s) {
    __builtin_amdgcn_global_load_lds((const __attribute__((address_space(1))) void*)g,
                                     (__attribute__((address_space(3))) void*)s, 16, 0, 0);
}

// Fused prep + plan. Blocks 0..2047: per-row sq + XS split. Block 2048:
// histogram+prefix plan, sOff, cls, yP init, ticket reset.
__global__ void prep_plan_kernel(const float* __restrict__ X, const int* __restrict__ y,
                                 float* __restrict__ sq, unsigned short* __restrict__ XS,
                                 int* __restrict__ plan, int* __restrict__ sOff,
                                 int* __restrict__ cls, int* __restrict__ yP,
                                 int* __restrict__ ticket) {
    __shared__ int hist[32][NCLS];
    __shared__ int sT[NCLS], sBase[NCLS];
    const int t = threadIdx.x;

    if (blockIdx.x < NTOT / 4) {
        int wave = t >> 6, lane = t & 63;
        int row = blockIdx.x * 4 + wave;
        float2 v = *(const float2*)(X + (size_t)row * 128 + lane * 2);
        __hip_bfloat16 h0 = __float2bfloat16(v.x);
        __hip_bfloat16 h1 = __float2bfloat16(v.y);
        float hf0 = __bfloat162float(h0), hf1 = __bfloat162float(h1);
        __hip_bfloat16 l0 = __float2bfloat16(v.x - hf0);
        __hip_bfloat16 l1 = __float2bfloat16(v.y - hf1);
        ushort2 hp, lp;
        hp.x = *(unsigned short*)&h0; hp.y = *(unsigned short*)&h1;
        lp.x = *(unsigned short*)&l0; lp.y = *(unsigned short*)&l1;
        *(ushort2*)(XS + (size_t)row * 256 + lane * 2) = hp;
        *(ushort2*)(XS + (size_t)row * 256 + 128 + lane * 2) = lp;
        float s = fmaf(v.x, v.x, v.y * v.y);
        #pragma unroll
        for (int off = 32; off > 0; off >>= 1) s += __shfl_down(s, off);
        if (lane == 0) sq[row] = s;
        return;
    }

    for (int i = t; i < 32 * NCLS; i += 256) (&hist[0][0])[i] = 0;
    for (int i = t; i < NPMAX; i += 256) yP[i] = -1;
    if (t == 0) *ticket = 0;
    __syncthreads();
    {
        const int base = t * 32;
        const int chunk = t >> 3;
        #pragma unroll 8
        for (int k = 0; k < 32; ++k)
            atomicAdd(&hist[chunk][y[base + k]], 1);
    }
    __syncthreads();
    if (t < NCLS) {
        int run = 0;
        #pragma unroll 8
        for (int b = 0; b < 32; ++b) {
            sOff[b * NCLS + t] = run;
            run += hist[b][t];
        }
        cls[t] = run;
        sT[t] = (run + 127) >> 7;
    }
    __syncthreads();
    if (t == 0) {
        int rowBase = 0, cum = 0;
        for (int q = 0; q < NCLS; ++q) {
            int T = sT[q];
            sBase[q] = rowBase;
            plan[q] = rowBase;
            plan[10 + q] = T;
            plan[20 + q] = T;
            plan[30 + q] = cum;
            rowBase += T << 7;
            cum += 2 * T * T;
        }
        plan[40] = cum;
    }
    __syncthreads();
    if (t < NCLS) {
        int rb = sBase[t];
        #pragma unroll 8
        for (int b = 0; b < 32; ++b) sOff[b * NCLS + t] += rb;
    }
}

// deterministic class-bucketed scatter: XS -> XSP (+ sqP, yP, idxP, invP)
__global__ void scatter_kernel(const int* __restrict__ y, const float* __restrict__ sq,
                               const unsigned short* __restrict__ XS,
                               const int* __restrict__ sOff,
                               unsigned short* __restrict__ XSP, float* __restrict__ sqP,
                               int* __restrict__ yP, int* __restrict__ idxP,
                               int* __restrict__ invP) {
    __shared__ int yloc[256];
    __shared__ int dstloc[256];
    const int b = blockIdx.x, t = threadIdx.x;
    const int gid = b * 256 + t;
    const int yv = y[gid];
    yloc[t] = yv;
    __syncthreads();
    int rank = 0;
    for (int k = 0; k < 256; ++k) rank += (k < t && yloc[k] == yv) ? 1 : 0;
    const int dst = sOff[b * NCLS + yv] + rank;
    dstloc[t] = dst;
    sqP[dst] = sq[gid];
    yP[dst] = yv;
    idxP[dst] = gid;
    invP[gid] = dst;
    __syncthreads();
    const int w = t >> 6, l = t & 63;
    for (int r = w; r < 256; r += 4) {
        int d = dstloc[r];
        *(ushort4*)(XSP + (size_t)d * 256 + l * 4) =
            *(const ushort4*)(XS + (size_t)(b * 256 + r) * 256 + l * 4);
    }
}

// Pass 1 (class-bucketed, 64x128 tiles): block -> (class c, i-half, j-tile).
__global__ __launch_bounds__(256, 2)
void pass1_kernel(const unsigned short* __restrict__ XSP, const int* __restrict__ yP,
                  const float* __restrict__ sqP, const int* __restrict__ plan,
                  float* __restrict__ top4pP) {
    const int bid = blockIdx.x;
    if (bid >= plan[40]) return;
    __shared__ __align__(16) char smem[49152];   // A dbuf 2x8K @0; B dbuf 2x16K @16384

    const int t = threadIdx.x;
    const int w = t >> 6, l = t & 63;
    const int wr = w >> 1, wc = w & 1;
    const int lg = l >> 4, lo16 = l & 15;

    int cc = 0;
    #pragma unroll
    for (int q = 1; q < NCLS; ++q) if (bid >= plan[30 + q]) cc = q;
    const int rowBase = plan[cc], T = plan[10 + cc];
    const int local = bid - plan[30 + cc];
    const int jt = local % T;
    const int itile2 = local / T;
    const int ibase = rowBase + (itile2 >> 1) * 128 + (itile2 & 1) * 64;
    const int jbase = rowBase + jt * 128;

    float sqi[8]; int yi[8];
    #pragma unroll
    for (int mi = 0; mi < 2; ++mi)
        #pragma unroll
        for (int r = 0; r < 4; ++r) {
            int row = ibase + wr * 32 + mi * 16 + lg * 4 + r;
            sqi[mi * 4 + r] = sqP[row];
            yi[mi * 4 + r] = yP[row];
        }
    float sqj[4]; int yj[4];
    #pragma unroll
    for (int ni = 0; ni < 4; ++ni) {
        int col = jbase + wc * 64 + ni * 16 + lo16;
        sqj[ni] = sqP[col];
        yj[ni] = yP[col];
    }

    const int swz = (lo16 & 7) << 4;
    unsigned aoff[2], boff[2];
    #pragma unroll
    for (int kk = 0; kk < 2; ++kk) {
        const int cA = (kk * 64 + lg * 16) ^ swz;
        aoff[kk] = (unsigned)((wr * 32 + lo16) * 128 + cA);
        boff[kk] = (unsigned)(16384 + (wc * 64 + lo16) * 128 + cA);
    }
    const int scol = ((t & 7) ^ ((t >> 3) & 7)) << 3;
    const int srow = t >> 3;   // 0..31

    auto STAGE = [&](int ks, int par) {
        if (ks < 2 || ks >= 4) {
            const int kA = (ks < 4) ? (ks & 1) * 64 : (ks - 2) * 64;
            const unsigned short* gA = XSP + (size_t)(ibase + srow) * 256 + kA + scol;
            char* dA = smem + par * 8192 + t * 16;
            gload_lds16(gA, dA);
            gload_lds16(gA + 32 * 256, dA + 4096);
        }
        const int kB = (ks < 4) ? ks * 64 : (ks - 4) * 64;
        const unsigned short* gB = XSP + (size_t)(jbase + srow) * 256 + kB + scol;
        char* dB = smem + 16384 + par * 16384 + t * 16;
        gload_lds16(gB, dB);
        gload_lds16(gB + 32 * 256, dB + 4096);
        gload_lds16(gB + 64 * 256, dB + 8192);
        gload_lds16(gB + 96 * 256, dB + 12288);
    };

    float tp0[8], tp1[8], tp2[8], tp3[8];
    #pragma unroll
    for (int c = 0; c < 8; ++c) {
        tp0[c] = 1e30f; tp1[c] = 1e30f; tp2[c] = 1e30f; tp3[c] = 1e30f;
    }

    f32x4 acc[2][4];
    f32x4 zz = {0.0f, 0.0f, 0.0f, 0.0f};
    #pragma unroll
    for (int mi = 0; mi < 2; ++mi)
        #pragma unroll
        for (int ni = 0; ni < 4; ++ni) acc[mi][ni] = zz;

    STAGE(0, 0);
    __syncthreads();

    #pragma unroll
    for (int ks = 0; ks < 6; ++ks) {
        const int par = ks & 1;
        if (ks < 5) STAGE(ks + 1, par ^ 1);
        #pragma unroll
        for (int kk = 0; kk < 2; ++kk) {
            short8 aF[2], bF[4];
            #pragma unroll
            for (int mi = 0; mi < 2; ++mi)
                aF[mi] = *(const short8*)(smem + aoff[kk] + par * 8192 + mi * 2048);
            #pragma unroll
            for (int ni = 0; ni < 4; ++ni)
                bF[ni] = *(const short8*)(smem + boff[kk] + par * 16384 + ni * 2048);
            #pragma unroll
            for (int mi = 0; mi < 2; ++mi)
                #pragma unroll
                for (int ni = 0; ni < 4; ++ni)
                    acc[mi][ni] = __builtin_amdgcn_mfma_f32_16x16x32_bf16(
                        aF[mi], bF[ni], acc[mi][ni], 0, 0, 0);
        }
        if (ks == 5) {
            #pragma unroll
            for (int mi = 0; mi < 2; ++mi)
                #pragma unroll
                for (int r = 0; r < 4; ++r) {
                    const int idx = mi * 4 + r;
                    #pragma unroll
                    for (int ni = 0; ni < 4; ++ni) {
                        float d2 = fmaf(-2.0f, acc[mi][ni][r], sqi[idx] + sqj[ni]);
                        d2 = fmaxf(d2, 0.0f);
                        float v = (yi[idx] == yj[ni]) ? d2 : 1e30f;
                        ins7(v, tp0[idx], tp1[idx], tp2[idx], tp3[idx]);
                    }
                }
        }
        __syncthreads();
    }

    // cross-lane + cross-wave merge -> slot jt
    float* scrR = (float*)smem;   // [64 rows][2 wc][4]
    #pragma unroll
    for (int idx = 0; idx < 8; ++idx) {
        float v0 = tp0[idx], v1 = tp1[idx], v2 = tp2[idx], v3 = tp3[idx];
        bmerge(1, v0, v1, v2, v3); bmerge(2, v0, v1, v2, v3);
        bmerge(4, v0, v1, v2, v3); bmerge(8, v0, v1, v2, v3);
        if (lo16 == 0) {
            int rl = wr * 32 + (idx >> 2) * 16 + lg * 4 + (idx & 3);
            float4 st; st.x = v0; st.y = v1; st.z = v2; st.w = v3;
            *(float4*)(scrR + rl * 8 + wc * 4) = st;
        }
    }
    __syncthreads();
    if (t < 64) {
        float4 qa = *(float4*)(scrR + t * 8);
        float4 qb = *(float4*)(scrR + t * 8 + 4);
        float b0 = qa.x, b1 = qa.y, b2 = qa.z, b3 = qa.w;
        ins7(qb.x, b0, b1, b2, b3); ins7(qb.y, b0, b1, b2, b3);
        ins7(qb.z, b0, b1, b2, b3); ins7(qb.w, b0, b1, b2, b3);
        size_t base = ((size_t)(ibase + t) * MAXSLOT + jt) * 4;
        top4pP[base + 0] = b0; top4pP[base + 1] = b1;
        top4pP[base + 2] = b2; top4pP[base + 3] = b3;
    }
}

// Pass 2: FULL-SQUARE count with FUSED anchor prologue. Each block computes
// anchors for its 128 i-rows from top4pP (via invP + plan nsl) — top-4 of a
// multiset is insertion-order independent, so values are bit-identical to the
// old anchorP kernel's. Engine unchanged (57.4 us / MfmaUtil 37%).
__global__ __launch_bounds__(256, 2)
void pass2_kernel(const unsigned short* __restrict__ XS, const float* __restrict__ sq,
                  const int* __restrict__ y, const int* __restrict__ invP,
                  const int* __restrict__ plan, const float* __restrict__ top4pP,
                  int* __restrict__ cntp) {
    __shared__ __align__(16) char smem[65536];

    const int t = threadIdx.x;
    const int w = t >> 6, l = t & 63;
    const int wr = w >> 1, wc = w & 1;
    const int lg = l >> 4, lo16 = l & 15;

    // XCD-aware bijective swizzle (512 % 8 == 0)
    const int bid = blockIdx.x;
    const int wg = (bid & 7) * ((NTIL * NJG) >> 3) + (bid >> 3);
    const int it = wg % NTIL, jg = wg / NTIL;
    const int ibase = it * 128;
    const int jg0 = jg * (128 * NJT);

    // fused anchor prologue: thread t<128 merges row ibase+t's slots
    {
        float* ancS = (float*)smem;
        if (t < 128) {
            int row = ibase + t;
            int nsl = plan[20 + y[row]];
            const float4* q4 = (const float4*)(top4pP + (size_t)invP[row] * MAXSLOT * 4);
            float b0 = 1e30f, b1 = 1e30f, b2 = 1e30f, b3 = 1e30f;
            for (int s = 0; s < nsl; ++s) {
                float4 q = q4[s];
                ins7(q.x, b0, b1, b2, b3); ins7(q.y, b0, b1, b2, b3);
                ins7(q.z, b0, b1, b2, b3); ins7(q.w, b0, b1, b2, b3);
            }
            ancS[t] = b3;
        }
        __syncthreads();
    }

    float sqi[16]; float anc[16];
    #pragma unroll
    for (int mi = 0; mi < 4; ++mi)
        #pragma unroll
        for (int r = 0; r < 4; ++r) {
            int rl = wr * 64 + mi * 16 + lg * 4 + r;
            sqi[mi * 4 + r] = sq[ibase + rl];
            anc[mi * 4 + r] = ((float*)smem)[rl];
        }
    __syncthreads();   // anc consumed; smem free for staging

    const int swz = (lo16 & 7) << 4;
    unsigned aoff[2], boff[2];
    #pragma unroll
    for (int kk = 0; kk < 2; ++kk) {
        const int cA = (kk * 64 + lg * 16) ^ swz;
        aoff[kk] = (unsigned)((wr * 64 + lo16) * 128 + cA);
        boff[kk] = (unsigned)(32768 + (wc * 64 + lo16) * 128 + cA);
    }
    const int srow = w * 32 + (l >> 3);
    const int scol = ((l & 7) ^ (l >> 3)) << 3;
    const unsigned short* gsrc = XS + (size_t)srow * 256 + scol;

    auto STAGE = [&](int jbase_rows, int ks, int par) {
        if (ks < 2 || ks >= 4) {
            const int kA = (ks < 4) ? (ks & 1) * 64 : (ks - 2) * 64;
            char* Ab = smem + par * 16384 + w * 4096;
            const unsigned short* gA = gsrc + (size_t)ibase * 256 + kA;
            #pragma unroll
            for (int q = 0; q < 4; ++q)
                gload_lds16(gA + (size_t)q * 8 * 256, Ab + q * 1024);
        }
        const int kB = (ks < 4) ? ks * 64 : (ks - 4) * 64;
        char* Bb = smem + 32768 + par * 16384 + w * 4096;
        const unsigned short* gB = gsrc + (size_t)jbase_rows * 256 + kB;
        #pragma unroll
        for (int q = 0; q < 4; ++q)
            gload_lds16(gB + (size_t)q * 8 * 256, Bb + q * 1024);
    };

    int cnt16[16];
    #pragma unroll
    for (int c = 0; c < 16; ++c) cnt16[c] = 0;

    STAGE(jg0, 0, 0);
    __syncthreads();

    #pragma unroll 1
    for (int jt = 0; jt < NJT; ++jt) {
        const int jbase = jg0 + jt * 128;
        float sqj[4];
        #pragma unroll
        for (int ni = 0; ni < 4; ++ni)
            sqj[ni] = sq[jbase + wc * 64 + ni * 16 + lo16];

        f32x4 acc[4][4];
        f32x4 zz = {0.0f, 0.0f, 0.0f, 0.0f};
        #pragma unroll
        for (int mi = 0; mi < 4; ++mi)
            #pragma unroll
            for (int ni = 0; ni < 4; ++ni) acc[mi][ni] = zz;

        #pragma unroll
        for (int ks = 0; ks < 6; ++ks) {
            const int par = ks & 1;
            if (ks < 5) STAGE(jbase, ks + 1, par ^ 1);
            else if (jt < NJT - 1) STAGE(jbase + 128, 0, par ^ 1);

            #pragma unroll
            for (int kk = 0; kk < 2; ++kk) {
                short8 aF[4], bF[4];
                #pragma unroll
                for (int mi = 0; mi < 4; ++mi)
                    aF[mi] = *(const short8*)(smem + aoff[kk] + par * 16384 + mi * 2048);
                #pragma unroll
                for (int ni = 0; ni < 4; ++ni)
                    bF[ni] = *(const short8*)(smem + boff[kk] + par * 16384 + ni * 2048);
                #pragma unroll
                for (int mi = 0; mi < 4; ++mi)
                    #pragma unroll
                    for (int ni = 0; ni < 4; ++ni)
                        acc[mi][ni] = __builtin_amdgcn_mfma_f32_16x16x32_bf16(
                            aF[mi], bF[ni], acc[mi][ni], 0, 0, 0);
            }

            if (ks == 5) {
                #pragma unroll
                for (int mi = 0; mi < 4; ++mi)
                    #pragma unroll
                    for (int r = 0; r < 4; ++r) {
                        const int idx = mi * 4 + r;
                        int c = 0;
                        #pragma unroll
                        for (int ni = 0; ni < 4; ++ni) {
                            float d2 = fmaf(-2.0f, acc[mi][ni][r], sqi[idx] + sqj[ni]);
                            d2 = fmaxf(d2, 0.0f);
                            c += (d2 <= anc[idx]) ? 1 : 0;
                        }
                        cnt16[idx] += c;
                    }
            }
            __syncthreads();
        }
    }

    int* scri = (int*)smem;  // [128][2]
    #pragma unroll
    for (int idx = 0; idx < 16; ++idx) {
        int c = cnt16[idx];
        c += __shfl_xor(c, 1); c += __shfl_xor(c, 2);
        c += __shfl_xor(c, 4); c += __shfl_xor(c, 8);
        if (lo16 == 0) {
            int rl = wr * 64 + (idx >> 2) * 16 + lg * 4 + (idx & 3);
            scri[rl * 2 + wc] = c;
        }
    }
    __syncthreads();
    if (t < 128) cntp[(size_t)(ibase + t) * NJG + jg] = scri[t * 2] + scri[t * 2 + 1];
}

// Fused reduce + finalize (last-block ticket; bit-identical output)
__global__ void reduce_fin_kernel(const int* __restrict__ cntp, const int* __restrict__ cls,
                                  float* __restrict__ partials, int* __restrict__ ticket,
                                  float* __restrict__ out) {
    __shared__ float red[256];
    __shared__ bool last;
    int t = threadIdx.x;
    int row = blockIdx.x * 256 + t;
    int s = 0;
    for (int c = 0; c < NJG; ++c) s += cntp[(size_t)row * NJG + c];
    red[t] = digammaf_dev((float)(s - 1));
    __syncthreads();
    for (int h = 128; h > 0; h >>= 1) {
        if (t < h) red[t] += red[t + h];
        __syncthreads();
    }
    if (t == 0) {
        partials[blockIdx.x] = red[0];
        __threadfence();
        int fin = atomicAdd(ticket, 1);
        last = (fin == (NTOT / 256) - 1);
    }
    __syncthreads();
    if (last && t == 0) {
        __threadfence();
        float acc = 0.0f;
        for (int c = 0; c < NTOT / 256; ++c) acc += partials[c];
        float Nf = (float)NTOT;
        float avg_m = acc / Nf;
        float avgNx = 0.0f;
        for (int c = 0; c < NCLS; ++c) {
            float nx = (float)cls[c];
            if (nx > 0.0f) avgNx += (nx / Nf) * digammaf_dev(nx);
        }
        float mi = digammaf_dev(Nf) - avgNx + digammaf_dev(3.0f) - avg_m;
        out[0] = fmaxf(mi / logf(2.0f), 0.0f);
    }
}

extern "C" void kernel_launch(void* const* d_in, const int* in_sizes, int n_in,
                              void* d_out, int out_size, void* d_ws, size_t ws_size,
                              hipStream_t stream) {
    const float* X = (const float*)d_in[0];
    const int* y = (const int*)d_in[1];
    float* out = (float*)d_out;

    float* sq       = (float*)d_ws;                                   // 8192
    float* partials = sq + NTOT;                                      // 32
    int*   cls      = (int*)(partials + 32);                          // 16
    int*   ticket   = cls + 16;                                       // 1 (+pad 319)
    int*   sOff     = ticket + 320;                                   // 320
    int*   plan     = sOff + 320;                                     // 48
    int*   yP       = plan + 48;                                      // 9472
    int*   idxP     = yP + NPMAX;                                     // 9472
    int*   invP     = idxP + NPMAX;                                   // 8192
    float* sqP      = (float*)(invP + NTOT);                          // 9472
    unsigned short* XS  = (unsigned short*)(sqP + NPMAX);             // 8192*256 (4 MB)
    unsigned short* XSP = XS + (size_t)NTOT * 256;                    // 9472*256 (4.85 MB)
    float* top4pP   = (float*)(XSP + (size_t)NPMAX * 256);            // 9472*32*4 (4.85 MB)
    int*   cntp     = (int*)(top4pP + (size_t)NPMAX * MAXSLOT * 4);   // 8192*8

    prep_plan_kernel<<<NTOT / 4 + 1, 256, 0, stream>>>(X, y, sq, XS, plan, sOff, cls, yP, ticket);
    scatter_kernel<<<NTOT / 256, 256, 0, stream>>>(y, sq, XS, sOff, XSP, sqP, yP, idxP, invP);
    pass1_kernel<<<G1, 256, 0, stream>>>(XSP, yP, sqP, plan, top4pP);
    pass2_kernel<<<NTIL * NJG, 256, 0, stream>>>(XS, sq, y, invP, plan, top4pP, cntp);
    reduce_fin_kernel<<<NTOT / 256, 256, 0, stream>>>(cntp, cls, partials, ticket, out);
}